// Round 6
// baseline (556.359 us; speedup 1.0000x reference)
//
#include <hip/hip_runtime.h>

typedef unsigned short u16;
typedef unsigned int   u32;
typedef _Float16       f16;

typedef f16   f16x8 __attribute__((ext_vector_type(8)));
typedef f16   f16x4 __attribute__((ext_vector_type(4)));
typedef float f32x4 __attribute__((ext_vector_type(4)));

#define LSTR 40  // LDS row stride (f16) for 128x32 GEMM tiles

__device__ __forceinline__ f32x4 mfma16(f16x8 a, f16x8 b, f32x4 c){
  return __builtin_amdgcn_mfma_f32_16x16x32_f16(a, b, c, 0, 0, 0);
}

// ============ 1. per-(b,c) spatial mean / rstd for content & style ============
__global__ __launch_bounds__(256) void k_mvn_stats(
    const float* __restrict__ content, const float* __restrict__ style,
    float* __restrict__ stats)
{
  const int src = blockIdx.x >> 11;
  const int row = blockIdx.x & 2047;
  const float* xp = (src ? style : content) + (size_t)row * 4096;
  const int t = threadIdx.x;
  double s = 0.0, ss = 0.0;
  for(int i = t * 4; i < 4096; i += 1024){
    float4 v = *(const float4*)(xp + i);
    s  += (double)v.x + (double)v.y + (double)v.z + (double)v.w;
    ss += (double)v.x * v.x + (double)v.y * v.y + (double)v.z * v.z + (double)v.w * v.w;
  }
  #pragma unroll
  for(int off = 32; off > 0; off >>= 1){
    s  += __shfl_xor(s, off);
    ss += __shfl_xor(ss, off);
  }
  __shared__ double sh[8];
  const int wid = t >> 6;
  if((t & 63) == 0){ sh[wid] = s; sh[4 + wid] = ss; }
  __syncthreads();
  if(t == 0){
    double S  = sh[0] + sh[1] + sh[2] + sh[3];
    double SS = sh[4] + sh[5] + sh[6] + sh[7];
    float mean = (float)(S * (1.0 / 4096.0));
    float var  = (float)((SS - S * S * (1.0 / 4096.0)) * (1.0 / 4095.0));
    stats[src * 4096 + row] = mean;
    stats[src * 4096 + 2048 + row] = rsqrtf(var + 1e-5f);
  }
}

// ============ 2. weight prep: W' = W*rstd (f16 hi[/lo]), b' = b - W.(mean*rstd) ============
__global__ __launch_bounds__(256) void k_prep_w1(
    const float* __restrict__ W, const float* __restrict__ B,
    const float* __restrict__ stats, int side,   // -1 none, 0 content, 1 style
    f16* __restrict__ outh, f16* __restrict__ outl,  // outl nullable
    float* __restrict__ bslice)                      // nullable; [4][512]
{
  const int b = blockIdx.y;
  const int o = blockIdx.x * 128 + (threadIdx.x >> 1);
  const int half = threadIdx.x & 1;
  const float* mp = (side >= 0) ? stats + side * 4096 + b * 512 : nullptr;
  const float* rp = (side >= 0) ? mp + 2048 : nullptr;
  f16* oh = outh + ((size_t)b * 512 + o) * 512 + half * 256;
  f16* ol = outl ? outl + ((size_t)b * 512 + o) * 512 + half * 256 : nullptr;
  float dot = 0.f;
  for(int i = 0; i < 256; i += 8){
    int c = half * 256 + i;
    float w[8];
    *(float4*)(w)     = *(const float4*)(W + (size_t)o * 512 + c);
    *(float4*)(w + 4) = *(const float4*)(W + (size_t)o * 512 + c + 4);
    f16x8 h8, l8;
    #pragma unroll
    for(int j = 0; j < 8; j++){
      float wp = w[j];
      if(side >= 0){
        float r = rp[c + j];
        dot += wp * mp[c + j] * r;
        wp *= r;
      }
      f16 h = (f16)wp;
      h8[j] = h; l8[j] = (f16)(wp - (float)h);
    }
    *(f16x8*)(oh + i) = h8;
    if(ol) *(f16x8*)(ol + i) = l8;
  }
  if(bslice){
    dot += __shfl_xor(dot, 1);
    if(half == 0) bslice[b * 512 + o] = B[o] - dot;
  }
}

// ============ 3. X prep: transpose [c][s] f32 -> Xt [s][c] f16 hi+lo ============
__global__ __launch_bounds__(256) void k_prep_x(
    const float* __restrict__ content, const float* __restrict__ style,
    f16* __restrict__ cth, f16* __restrict__ ctl,
    f16* __restrict__ sth, f16* __restrict__ stl)
{
  const int side = blockIdx.z;
  const int b = blockIdx.y;
  const int s0 = blockIdx.x * 128;
  const float* Xb = (side ? style : content) + (size_t)b * 512 * 4096;
  f16* Oh = (side ? sth : cth) + (size_t)b * 4096 * 512;
  f16* Ol = (side ? stl : ctl) + (size_t)b * 4096 * 512;
  __shared__ float Xs[32][132];
  const int t = threadIdx.x;
  const int s = t >> 1, half = t & 1;
  for(int cc = 0; cc < 512; cc += 32){
    __syncthreads();
    #pragma unroll
    for(int u = 0; u < 4; u++){
      int q = t + u * 256;
      int row = q >> 5, f4 = q & 31;
      float4 v = *(const float4*)(Xb + (size_t)(cc + row) * 4096 + s0 + f4 * 4);
      *(float4*)(&Xs[row][f4 * 4]) = v;
    }
    __syncthreads();
    f16x8 h0, h1, l0, l1;
    #pragma unroll
    for(int i = 0; i < 8; i++){
      float x = Xs[half * 16 + i][s];
      f16 h = (f16)x; h0[i] = h; l0[i] = (f16)(x - (float)h);
    }
    #pragma unroll
    for(int i = 0; i < 8; i++){
      float x = Xs[half * 16 + 8 + i][s];
      f16 h = (f16)x; h1[i] = h; l1[i] = (f16)(x - (float)h);
    }
    size_t o = (size_t)(s0 + s) * 512 + cc + half * 16;
    *(f16x8*)(Oh + o) = h0; *(f16x8*)(Oh + o + 8) = h1;
    *(f16x8*)(Ol + o) = l0; *(f16x8*)(Ol + o + 8) = l1;
  }
}

// ============ 4. conv1x1 GEMM single-pass: C = W' . Xt^T + b', f16 natural out ============
__global__ __launch_bounds__(256) void k_convT(
    const f16* __restrict__ Xt, const f16* __restrict__ Wp,
    const float* __restrict__ bias, int bw, f16* __restrict__ Out)
{
  const int b = blockIdx.z;
  const int o0 = blockIdx.y * 128;
  const int s0 = blockIdx.x * 128;
  const f16* Xb = Xt + (size_t)b * 4096 * 512;
  const f16* Wb = Wp + (bw ? (size_t)b * 262144 : 0);
  const float* bp = bias + (bw ? b * 512 : 0);
  f16* Ob = Out + (size_t)b * 512 * 4096;
  __shared__ f16 As[128 * LSTR];
  __shared__ f16 Bs[128 * LSTR];
  const int t = threadIdx.x;
  const int lane = t & 63, wid = t >> 6;
  const int wm = (wid >> 1) * 64, wn = (wid & 1) * 64;
  const int lr = lane & 15, lg = lane >> 4;
  f32x4 acc[4][4] = {};
  for(int kk = 0; kk < 512; kk += 32){
    __syncthreads();
    #pragma unroll
    for(int rep = 0; rep < 2; rep++){
      int q = t + 256 * rep;
      int row = q >> 2, ch = (q & 3) * 8;
      *(f16x8*)(As + row * LSTR + ch) = *(const f16x8*)(Wb + (size_t)(o0 + row) * 512 + kk + ch);
      *(f16x8*)(Bs + row * LSTR + ch) = *(const f16x8*)(Xb + (size_t)(s0 + row) * 512 + kk + ch);
    }
    __syncthreads();
    f16x8 av[4], bv[4];
    #pragma unroll
    for(int mi = 0; mi < 4; mi++)
      av[mi] = *(const f16x8*)(As + (wm + mi * 16 + lr) * LSTR + lg * 8);
    #pragma unroll
    for(int ni = 0; ni < 4; ni++)
      bv[ni] = *(const f16x8*)(Bs + (wn + ni * 16 + lr) * LSTR + lg * 8);
    #pragma unroll
    for(int mi = 0; mi < 4; mi++){
      #pragma unroll
      for(int ni = 0; ni < 4; ni++)
        acc[mi][ni] = mfma16(av[mi], bv[ni], acc[mi][ni]);
    }
  }
  #pragma unroll
  for(int mi = 0; mi < 4; mi++){
    #pragma unroll
    for(int ni = 0; ni < 4; ni++){
      #pragma unroll
      for(int j = 0; j < 4; j++){
        int o = o0 + wm + mi * 16 + lg * 4 + j;
        int s = s0 + wn + ni * 16 + lr;
        Ob[(size_t)o * 4096 + s] = (f16)(acc[mi][ni][j] + bp[o]);
      }
    }
  }
}

// ============ 5. conv1x1 GEMM split-3 (hi/lo), hi/lo f16 natural outputs ============
__global__ __launch_bounds__(256) void k_convT3(
    const f16* __restrict__ Xh, const f16* __restrict__ Xl,
    const f16* __restrict__ Wh, const f16* __restrict__ Wl,
    const float* __restrict__ bias, f16* __restrict__ Oh, f16* __restrict__ Ol)
{
  const int b = blockIdx.z;
  const int o0 = blockIdx.y * 128;
  const int s0 = blockIdx.x * 128;
  const f16* Xhb = Xh + (size_t)b * 4096 * 512;
  const f16* Xlb = Xl + (size_t)b * 4096 * 512;
  const f16* Whb = Wh + (size_t)b * 262144;
  const f16* Wlb = Wl + (size_t)b * 262144;
  const float* bp = bias + b * 512;
  f16* Ohb = Oh + (size_t)b * 512 * 4096;
  f16* Olb = Ol + (size_t)b * 512 * 4096;
  __shared__ f16 Ah[128 * LSTR], Al[128 * LSTR], Bh[128 * LSTR], Bl[128 * LSTR];
  const int t = threadIdx.x;
  const int lane = t & 63, wid = t >> 6;
  const int wm = (wid >> 1) * 64, wn = (wid & 1) * 64;
  const int lr = lane & 15, lg = lane >> 4;
  f32x4 acc[4][4] = {};
  for(int kk = 0; kk < 512; kk += 32){
    __syncthreads();
    #pragma unroll
    for(int rep = 0; rep < 2; rep++){
      int q = t + 256 * rep;
      int row = q >> 2, ch = (q & 3) * 8;
      size_t wsrc = (size_t)(o0 + row) * 512 + kk + ch;
      size_t xsrc = (size_t)(s0 + row) * 512 + kk + ch;
      *(f16x8*)(Ah + row * LSTR + ch) = *(const f16x8*)(Whb + wsrc);
      *(f16x8*)(Al + row * LSTR + ch) = *(const f16x8*)(Wlb + wsrc);
      *(f16x8*)(Bh + row * LSTR + ch) = *(const f16x8*)(Xhb + xsrc);
      *(f16x8*)(Bl + row * LSTR + ch) = *(const f16x8*)(Xlb + xsrc);
    }
    __syncthreads();
    f16x8 ah[4], alo[4], bh[4], blo[4];
    #pragma unroll
    for(int mi = 0; mi < 4; mi++){
      ah[mi]  = *(const f16x8*)(Ah + (wm + mi * 16 + lr) * LSTR + lg * 8);
      alo[mi] = *(const f16x8*)(Al + (wm + mi * 16 + lr) * LSTR + lg * 8);
    }
    #pragma unroll
    for(int ni = 0; ni < 4; ni++){
      bh[ni]  = *(const f16x8*)(Bh + (wn + ni * 16 + lr) * LSTR + lg * 8);
      blo[ni] = *(const f16x8*)(Bl + (wn + ni * 16 + lr) * LSTR + lg * 8);
    }
    #pragma unroll
    for(int mi = 0; mi < 4; mi++){
      #pragma unroll
      for(int ni = 0; ni < 4; ni++){
        f32x4 a = acc[mi][ni];
        a = mfma16(ah[mi],  bh[ni],  a);
        a = mfma16(ah[mi],  blo[ni], a);
        a = mfma16(alo[mi], bh[ni],  a);
        acc[mi][ni] = a;
      }
    }
  }
  #pragma unroll
  for(int mi = 0; mi < 4; mi++){
    #pragma unroll
    for(int ni = 0; ni < 4; ni++){
      #pragma unroll
      for(int j = 0; j < 4; j++){
        int o = o0 + wm + mi * 16 + lg * 4 + j;
        int s = s0 + wn + ni * 16 + lr;
        float v = acc[mi][ni][j] + bp[o];
        f16 h = (f16)v;
        Ohb[(size_t)o * 4096 + s] = h;
        Olb[(size_t)o * 4096 + s] = (f16)(v - (float)h);
      }
    }
  }
}

// ============ 6. DA aggregation (unchanged; natural inputs) ============
__global__ __launch_bounds__(256) void k_da1(
    const f16* __restrict__ K, const f16* __restrict__ V,
    const float* __restrict__ alpha_p, const float* __restrict__ beta_p,
    float* __restrict__ kagg, float* __restrict__ vagg)
{
  const int x = blockIdx.x & 63, bh = blockIdx.x >> 6;
  const f16* Kb = K + (size_t)bh * 64 * 4096;
  const f16* Vb = V + (size_t)bh * 64 * 4096;
  __shared__ float kl[64][65];
  __shared__ float vl[64][65];
  __shared__ float kc[64], vc[64], simv[64];
  const int t = threadIdx.x;
  const int c = t >> 2, yp = t & 3;
  const int xb = (x >> 3) * 512 + (x & 7) * 8;
  #pragma unroll
  for(int u = 0; u < 2; u++){
    int yh = yp * 2 + u;
    f16x8 k8 = *(const f16x8*)(Kb + (size_t)c * 4096 + xb + yh * 64);
    f16x8 v8 = *(const f16x8*)(Vb + (size_t)c * 4096 + xb + yh * 64);
    #pragma unroll
    for(int j = 0; j < 8; j++){
      kl[c][yh * 8 + j] = (float)k8[j];
      vl[c][yh * 8 + j] = (float)v8[j];
    }
  }
  __syncthreads();
  float sk = 0.f, sv = 0.f;
  for(int yy = yp * 16; yy < yp * 16 + 16; yy++){ sk += kl[c][yy]; sv += vl[c][yy]; }
  sk += __shfl_xor(sk, 1); sk += __shfl_xor(sk, 2);
  sv += __shfl_xor(sv, 1); sv += __shfl_xor(sv, 2);
  if(yp == 0){ kc[c] = sk * (1.f / 64.f); vc[c] = sv * (1.f / 64.f); }
  __syncthreads();
  const int y = t >> 2, cp = t & 3;
  float d = 0.f;
  for(int cc = cp * 16; cc < cp * 16 + 16; cc++) d += kc[cc] * kl[cc][y];
  d += __shfl_xor(d, 1); d += __shfl_xor(d, 2);
  if(cp == 0) simv[y] = 1.f / (1.f + expf(-(beta_p[0] + alpha_p[0] * d)));
  __syncthreads();
  float ak = 0.f, av = 0.f;
  for(int yy = yp * 16; yy < yp * 16 + 16; yy++){
    float sm = simv[yy];
    ak += sm * kl[c][yy]; av += sm * vl[c][yy];
  }
  ak += __shfl_xor(ak, 1); ak += __shfl_xor(ak, 2);
  av += __shfl_xor(av, 1); av += __shfl_xor(av, 2);
  if(yp == 0){
    size_t o = ((size_t)bh * 64 + x) * 64 + c;
    kagg[o] = (ak + kc[c]) * (1.f / 65.f);
    vagg[o] = (av + vc[c]) * (1.f / 65.f);
  }
}

// ============ 7. DA attention MFMA; output TRANSPOSED [s][c] for final ============
__global__ __launch_bounds__(256) void k_da2(
    const f16* __restrict__ Q, const float* __restrict__ kagg,
    const float* __restrict__ vagg, f16* __restrict__ OutT)
{
  const int bh = blockIdx.x >> 4;
  const int s0 = (blockIdx.x & 15) << 8;
  const int b_ = bh >> 3, hd = bh & 7;
  const f16* Qb = Q + (size_t)bh * 64 * 4096;
  f16* Ot = OutT + (size_t)b_ * 4096 * 512 + hd * 64;

  __shared__ __align__(16) f16 Qt[256][72];
  __shared__ __align__(16) f16 Kt[64][72];
  __shared__ __align__(16) f16 Vt[64][72];
  const int t = threadIdx.x;
  const int lane = t & 63, w = t >> 6;
  const int lr = lane & 15, lg = lane >> 4;

  {
    const int so = t & 31;
    #pragma unroll
    for(int pass = 0; pass < 8; pass++){
      int c = (t >> 5) + pass * 8;
      f16x8 q8 = *(const f16x8*)(Qb + (size_t)c * 4096 + s0 + so * 8);
      #pragma unroll
      for(int j = 0; j < 8; j++){
        int s = so * 8 + j;
        int col = (((c >> 3) ^ (s & 7)) << 3) | (c & 7);
        Qt[s][col] = q8[j];
      }
    }
  }
  {
    const int z = t >> 2, c0 = (t & 3) * 16;
    #pragma unroll
    for(int u = 0; u < 4; u++){
      float4 v = *(const float4*)(kagg + (size_t)bh * 4096 + z * 64 + c0 + u * 4);
      float vv[4] = {v.x, v.y, v.z, v.w};
      #pragma unroll
      for(int j = 0; j < 4; j++){
        int c = c0 + u * 4 + j;
        int col = (((c >> 3) ^ (z & 7)) << 3) | (c & 7);
        Kt[z][col] = (f16)vv[j];
      }
    }
    #pragma unroll
    for(int u = 0; u < 4; u++){
      float4 v = *(const float4*)(vagg + (size_t)bh * 4096 + z * 64 + c0 + u * 4);
      float vv[4] = {v.x, v.y, v.z, v.w};
      #pragma unroll
      for(int j = 0; j < 4; j++){
        int c = c0 + u * 4 + j;
        int col = (((z >> 3) ^ (c & 7)) << 3) | (z & 7);
        Vt[c][col] = (f16)vv[j];
      }
    }
  }
  __syncthreads();

  f32x4 acc[4][4] = {};
  #pragma unroll
  for(int kc = 0; kc < 2; kc++){
    f16x8 af[4], bf[4];
    #pragma unroll
    for(int mi = 0; mi < 4; mi++){
      int row = w * 64 + mi * 16 + lr;
      af[mi] = *(const f16x8*)(&Qt[row][(((kc * 4 + lg) ^ (row & 7)) << 3)]);
    }
    #pragma unroll
    for(int ni = 0; ni < 4; ni++){
      int row = ni * 16 + lr;
      bf[ni] = *(const f16x8*)(&Kt[row][(((kc * 4 + lg) ^ (row & 7)) << 3)]);
    }
    #pragma unroll
    for(int mi = 0; mi < 4; mi++){
      #pragma unroll
      for(int ni = 0; ni < 4; ni++)
        acc[mi][ni] = mfma16(af[mi], bf[ni], acc[mi][ni]);
    }
  }

  #pragma unroll
  for(int mi = 0; mi < 4; mi++){
    #pragma unroll
    for(int j = 0; j < 4; j++){
      float v0 = acc[mi][0][j], v1 = acc[mi][1][j], v2 = acc[mi][2][j], v3 = acc[mi][3][j];
      float m = fmaxf(fmaxf(v0, v1), fmaxf(v2, v3));
      m = fmaxf(m, __shfl_xor(m, 1)); m = fmaxf(m, __shfl_xor(m, 2));
      m = fmaxf(m, __shfl_xor(m, 4)); m = fmaxf(m, __shfl_xor(m, 8));
      float e0 = expf(v0 - m), e1 = expf(v1 - m), e2 = expf(v2 - m), e3 = expf(v3 - m);
      float sm = e0 + e1 + e2 + e3;
      sm += __shfl_xor(sm, 1); sm += __shfl_xor(sm, 2);
      sm += __shfl_xor(sm, 4); sm += __shfl_xor(sm, 8);
      float inv = 1.f / sm;
      float ev[4] = {e0, e1, e2, e3};
      int row = w * 64 + mi * 16 + lg * 4 + j;
      #pragma unroll
      for(int ni = 0; ni < 4; ni++){
        int z = lr + 16 * ni;
        int col = (((z >> 3) ^ (row & 7)) << 3) | (z & 7);
        Qt[row][col] = (f16)(ev[ni] * inv);
      }
    }
  }
  // no barrier: each wave touches only its own Qt rows; Kt/Vt read-only

  f32x4 acc2[4][4] = {};
  #pragma unroll
  for(int kc = 0; kc < 2; kc++){
    f16x8 af[4], bf[4];
    #pragma unroll
    for(int mi = 0; mi < 4; mi++){
      int row = w * 64 + mi * 16 + lr;
      af[mi] = *(const f16x8*)(&Qt[row][(((kc * 4 + lg) ^ (row & 7)) << 3)]);
    }
    #pragma unroll
    for(int ni = 0; ni < 4; ni++){
      int row = ni * 16 + lr;
      bf[ni] = *(const f16x8*)(&Vt[row][(((kc * 4 + lg) ^ (row & 7)) << 3)]);
    }
    #pragma unroll
    for(int mi = 0; mi < 4; mi++){
      #pragma unroll
      for(int ni = 0; ni < 4; ni++)
        acc2[mi][ni] = mfma16(af[mi], bf[ni], acc2[mi][ni]);
    }
  }

  // transposed store: OutT[(s)*512 + hd*64 + c]
  #pragma unroll
  for(int mi = 0; mi < 4; mi++){
    #pragma unroll
    for(int j = 0; j < 4; j++){
      size_t srow = (size_t)(s0 + w * 64 + mi * 16 + lg * 4 + j) * 512;
      #pragma unroll
      for(int ni = 0; ni < 4; ni++)
        Ot[srow + ni * 16 + lr] = (f16)acc2[mi][ni][j];
    }
  }
}

// ============ 8. PA1 split-K MFMA (unchanged; natural inputs) ============
__global__ __launch_bounds__(256) void k_pa1(
    const f16* __restrict__ Qh, const f16* __restrict__ Ql,
    const f16* __restrict__ Kh, const f16* __restrict__ Kl,
    float* __restrict__ pa1p)
{
  const int slice = blockIdx.x & 7;
  const int bh = blockIdx.x >> 3;
  const size_t base = (size_t)bh * 64 * 4096;
  __shared__ f16 Ah[2][64][72], Al[2][64][72], Bh[2][64][72], Bl[2][64][72];
  const int t = threadIdx.x;
  const int lane = t & 63, wid = t >> 6;
  const int wm = (wid >> 1) * 32, wn = (wid & 1) * 32;
  const int lr = lane & 15, lg = lane >> 4;
  f32x4 acc[2][2] = {};
  for(int chunk = 0; chunk < 4; chunk++){
    const int c0 = slice * 8 + chunk * 2;
    __syncthreads();
    #pragma unroll
    for(int cc = 0; cc < 2; cc++){
      size_t cbase = base + (size_t)(c0 + cc) * 4096;
      #pragma unroll
      for(int u = 0; u < 2; u++){
        int e = u * 256 + t;
        int x = e >> 3, yh = e & 7;
        size_t src = cbase + (size_t)((x >> 3) * 512 + (x & 7) * 8 + yh * 64);
        int dst = yh * 8;
        *(f16x8*)(&Ah[cc][x][dst]) = *(const f16x8*)(Qh + src);
        *(f16x8*)(&Al[cc][x][dst]) = *(const f16x8*)(Ql + src);
        *(f16x8*)(&Bh[cc][x][dst]) = *(const f16x8*)(Kh + src);
        *(f16x8*)(&Bl[cc][x][dst]) = *(const f16x8*)(Kl + src);
      }
    }
    __syncthreads();
    #pragma unroll
    for(int cc = 0; cc < 2; cc++){
      #pragma unroll
      for(int kc = 0; kc < 2; kc++){
        f16x8 ah[2], alo[2], bh[2], blo[2];
        #pragma unroll
        for(int mi = 0; mi < 2; mi++){
          ah[mi]  = *(const f16x8*)(&Ah[cc][wm + mi * 16 + lr][kc * 32 + lg * 8]);
          alo[mi] = *(const f16x8*)(&Al[cc][wm + mi * 16 + lr][kc * 32 + lg * 8]);
        }
        #pragma unroll
        for(int ni = 0; ni < 2; ni++){
          bh[ni]  = *(const f16x8*)(&Bh[cc][wn + ni * 16 + lr][kc * 32 + lg * 8]);
          blo[ni] = *(const f16x8*)(&Bl[cc][wn + ni * 16 + lr][kc * 32 + lg * 8]);
        }
        #pragma unroll
        for(int mi = 0; mi < 2; mi++){
          #pragma unroll
          for(int ni = 0; ni < 2; ni++){
            f32x4 a = acc[mi][ni];
            a = mfma16(ah[mi],  bh[ni],  a);
            a = mfma16(ah[mi],  blo[ni], a);
            a = mfma16(alo[mi], bh[ni],  a);
            acc[mi][ni] = a;
          }
        }
      }
    }
  }
  float* outp = pa1p + ((size_t)bh * 8 + slice) * 4096;
  #pragma unroll
  for(int mi = 0; mi < 2; mi++){
    #pragma unroll
    for(int ni = 0; ni < 2; ni++){
      #pragma unroll
      for(int j = 0; j < 4; j++){
        int x = wm + mi * 16 + lg * 4 + j;
        int z = wn + ni * 16 + lr;
        outp[x * 64 + z] = acc[mi][ni][j];
      }
    }
  }
}

// ============ 8b. reduce partials + argmax ============
__global__ __launch_bounds__(64) void k_pa1r(
    const float* __restrict__ pa1p, int* __restrict__ idx)
{
  const int bh = blockIdx.x;
  const int x = threadIdx.x;
  const float* p = pa1p + (size_t)bh * 8 * 4096 + x * 64;
  float best = -1e30f; int bi = 0;
  for(int z = 0; z < 64; z += 4){
    float4 v = *(const float4*)(p + z);
    #pragma unroll
    for(int sl = 1; sl < 8; sl++){
      float4 w = *(const float4*)(p + sl * 4096 + z);
      v.x += w.x; v.y += w.y; v.z += w.z; v.w += w.w;
    }
    if(v.x > best){ best = v.x; bi = z; }
    if(v.y > best){ best = v.y; bi = z + 1; }
    if(v.z > best){ best = v.z; bi = z + 2; }
    if(v.w > best){ best = v.w; bi = z + 3; }
  }
  idx[bh * 64 + x] = bi;
}

// ============ 9. PA intra-block attention; output TRANSPOSED [s][c] ============
__global__ __launch_bounds__(256) void k_pa2(
    const f16* __restrict__ Qh, const f16* __restrict__ Kh,
    const f16* __restrict__ V2, const int* __restrict__ idx, f16* __restrict__ OutT)
{
  const int hw = blockIdx.x;
  const int bh = (hw & 7) * 4 + ((hw >> 3) >> 6);
  const int x  = (hw >> 3) & 63;
  const int b_ = bh >> 3, hd = bh & 7;
  const size_t base = (size_t)bh * 64 * 4096;
  f16* Ot = OutT + (size_t)b_ * 4096 * 512 + hd * 64;

  __shared__ __align__(16) char Ubuf[18432];
  __shared__ f16 Vn[64][72];
  __shared__ f16 Ps[64][72];
  f16   (*Qt)[72] = (f16(*)[72])Ubuf;
  f16   (*Kt)[72] = (f16(*)[72])(Ubuf + 9216);
  float (*Lf)[66] = (float(*)[66])Ubuf;
  float (*Os)[67] = (float(*)[67])Ubuf;

  const int t = threadIdx.x;
  const int lane = t & 63, wid = t >> 6;
  const int wm = (wid >> 1) * 32, wn = (wid & 1) * 32;
  const int lr = lane & 15, lg = lane >> 4;

  const int xk = idx[bh * 64 + x];
  const int xb = (x >> 3) * 512 + (x & 7) * 8;
  const int kb = (xk >> 3) * 512 + (xk & 7) * 8;

  {
    const int c = t >> 2, q4 = t & 3;
    #pragma unroll
    for(int u = 0; u < 2; u++){
      int yh = q4 * 2 + u;
      f16x8 q8 = *(const f16x8*)(Qh + base + (size_t)c * 4096 + xb + yh * 64);
      f16x8 k8 = *(const f16x8*)(Kh + base + (size_t)c * 4096 + kb + yh * 64);
      f16x8 v8 = *(const f16x8*)(V2 + base + (size_t)c * 4096 + kb + yh * 64);
      int col = ((((c >> 3) ^ yh) & 7) << 3) + (c & 7);
      #pragma unroll
      for(int j = 0; j < 8; j++){
        Qt[yh * 8 + j][col] = q8[j];
        Kt[yh * 8 + j][col] = k8[j];
      }
      *(f16x8*)(&Vn[c][yh * 8]) = v8;
    }
  }
  __syncthreads();

  f32x4 acc[2][2] = {};
  #pragma unroll
  for(int kc = 0; kc < 2; kc++){
    f16x8 af[2], bf[2];
    #pragma unroll
    for(int mi = 0; mi < 2; mi++){
      int row = wm + mi * 16 + lr;
      af[mi] = *(const f16x8*)(&Qt[row][((((kc * 4 + lg) ^ (row >> 3)) & 7) << 3)]);
    }
    #pragma unroll
    for(int ni = 0; ni < 2; ni++){
      int row = wn + ni * 16 + lr;
      bf[ni] = *(const f16x8*)(&Kt[row][((((kc * 4 + lg) ^ (row >> 3)) & 7) << 3)]);
    }
    #pragma unroll
    for(int mi = 0; mi < 2; mi++){
      #pragma unroll
      for(int ni = 0; ni < 2; ni++)
        acc[mi][ni] = mfma16(af[mi], bf[ni], acc[mi][ni]);
    }
  }
  __syncthreads();
  #pragma unroll
  for(int mi = 0; mi < 2; mi++){
    #pragma unroll
    for(int ni = 0; ni < 2; ni++){
      #pragma unroll
      for(int j = 0; j < 4; j++)
        Lf[wm + mi * 16 + lg * 4 + j][wn + ni * 16 + lr] = acc[mi][ni][j];
    }
  }
  __syncthreads();

  {
    const int y = t >> 2, zp = t & 3;
    float l[16];
    #pragma unroll
    for(int i = 0; i < 16; i++) l[i] = Lf[y][zp * 16 + i];
    float m = l[0];
    #pragma unroll
    for(int i = 1; i < 16; i++) m = fmaxf(m, l[i]);
    m = fmaxf(m, __shfl_xor(m, 1)); m = fmaxf(m, __shfl_xor(m, 2));
    float sum = 0.f;
    #pragma unroll
    for(int i = 0; i < 16; i++){ l[i] = expf(l[i] - m); sum += l[i]; }
    sum += __shfl_xor(sum, 1); sum += __shfl_xor(sum, 2);
    float inv = 1.f / sum;
    f16x8 p0, p1;
    #pragma unroll
    for(int i = 0; i < 8; i++){ p0[i] = (f16)(l[i] * inv); p1[i] = (f16)(l[8 + i] * inv); }
    *(f16x8*)(&Ps[y][zp * 16]) = p0;
    *(f16x8*)(&Ps[y][zp * 16 + 8]) = p1;
  }
  __syncthreads();

  f32x4 acc2[2][2] = {};
  #pragma unroll
  for(int kc = 0; kc < 2; kc++){
    f16x8 af[2], bf[2];
    #pragma unroll
    for(int mi = 0; mi < 2; mi++)
      af[mi] = *(const f16x8*)(&Ps[wm + mi * 16 + lr][kc * 32 + lg * 8]);
    #pragma unroll
    for(int ni = 0; ni < 2; ni++)
      bf[ni] = *(const f16x8*)(&Vn[wn + ni * 16 + lr][kc * 32 + lg * 8]);
    #pragma unroll
    for(int mi = 0; mi < 2; mi++){
      #pragma unroll
      for(int ni = 0; ni < 2; ni++)
        acc2[mi][ni] = mfma16(af[mi], bf[ni], acc2[mi][ni]);
    }
  }
  #pragma unroll
  for(int mi = 0; mi < 2; mi++){
    #pragma unroll
    for(int ni = 0; ni < 2; ni++){
      #pragma unroll
      for(int j = 0; j < 4; j++)
        Os[wn + ni * 16 + lr][wm + mi * 16 + lg * 4 + j] = acc2[mi][ni][j];
    }
  }
  __syncthreads();

  // transposed store: OutT[(s(y))*512 + hd*64 + c], 32B runs along c
  {
    const int y = t >> 2, cq = (t & 3) * 16;
    size_t srow = (size_t)(xb + (y >> 3) * 64 + (y & 7)) * 512;
    f16x8 w0, w1;
    #pragma unroll
    for(int i = 0; i < 8; i++){ w0[i] = (f16)Os[cq + i][y]; w1[i] = (f16)Os[cq + 8 + i][y]; }
    *(f16x8*)(Ot + srow + cq) = w0;
    *(f16x8*)(Ot + srow + cq + 8) = w1;
  }
}

// ============ 10. Final: f1'.DA_t + f2'.PA_t + biases + content -> f32 ============
__global__ __launch_bounds__(256) void k_finalT(
    const f16* __restrict__ X1t, const f16* __restrict__ X2t,
    const f16* __restrict__ W1p, const f16* __restrict__ W2p,
    const float* __restrict__ B1, const float* __restrict__ B2,
    const float* __restrict__ content, float* __restrict__ out)
{
  const int b = blockIdx.z;
  const int o0 = blockIdx.y * 128;
  const int s0 = blockIdx.x * 128;
  __shared__ f16 As[128 * LSTR];
  __shared__ f16 Bs[128 * LSTR];
  const int t = threadIdx.x;
  const int lane = t & 63, wid = t >> 6;
  const int wm = (wid >> 1) * 64, wn = (wid & 1) * 64;
  const int lr = lane & 15, lg = lane >> 4;
  f32x4 acc[4][4] = {};
  for(int pass = 0; pass < 2; pass++){
    const f16* Xb = (pass ? X2t : X1t) + (size_t)b * 4096 * 512;
    const f16* Wb = pass ? W2p : W1p;
    for(int kk = 0; kk < 512; kk += 32){
      __syncthreads();
      #pragma unroll
      for(int rep = 0; rep < 2; rep++){
        int q = t + 256 * rep;
        int row = q >> 2, ch = (q & 3) * 8;
        *(f16x8*)(As + row * LSTR + ch) = *(const f16x8*)(Wb + (size_t)(o0 + row) * 512 + kk + ch);
        *(f16x8*)(Bs + row * LSTR + ch) = *(const f16x8*)(Xb + (size_t)(s0 + row) * 512 + kk + ch);
      }
      __syncthreads();
      f16x8 av[4], bv[4];
      #pragma unroll
      for(int mi = 0; mi < 4; mi++)
        av[mi] = *(const f16x8*)(As + (wm + mi * 16 + lr) * LSTR + lg * 8);
      #pragma unroll
      for(int ni = 0; ni < 4; ni++)
        bv[ni] = *(const f16x8*)(Bs + (wn + ni * 16 + lr) * LSTR + lg * 8);
      #pragma unroll
      for(int mi = 0; mi < 4; mi++){
        #pragma unroll
        for(int ni = 0; ni < 4; ni++)
          acc[mi][ni] = mfma16(av[mi], bv[ni], acc[mi][ni]);
      }
    }
  }
  #pragma unroll
  for(int mi = 0; mi < 4; mi++){
    #pragma unroll
    for(int ni = 0; ni < 4; ni++){
      #pragma unroll
      for(int j = 0; j < 4; j++){
        int o = o0 + wm + mi * 16 + lg * 4 + j;
        int s = s0 + wn + ni * 16 + lr;
        size_t gi = ((size_t)b * 512 + o) * 4096 + s;
        out[gi] = acc[mi][ni][j] + B1[o] + B2[o] + content[gi];
      }
    }
  }
}

extern "C" void kernel_launch(void* const* d_in, const int* in_sizes, int n_in,
                              void* d_out, int out_size, void* d_ws, size_t ws_size,
                              hipStream_t stream) {
  (void)in_sizes; (void)n_in; (void)out_size; (void)ws_size;
  const float* content = (const float*)d_in[0];
  const float* style   = (const float*)d_in[1];
  const float* q_w  = (const float*)d_in[2];  const float* q_b  = (const float*)d_in[3];
  const float* k_w  = (const float*)d_in[4];  const float* k_b  = (const float*)d_in[5];
  const float* v_w  = (const float*)d_in[6];  const float* v_b  = (const float*)d_in[7];
  const float* q2_w = (const float*)d_in[8];  const float* q2_b = (const float*)d_in[9];
  const float* k2_w = (const float*)d_in[10]; const float* k2_b = (const float*)d_in[11];
  const float* v2_w = (const float*)d_in[12]; const float* v2_b = (const float*)d_in[13];
  const float* f1_w = (const float*)d_in[14]; const float* f1_b = (const float*)d_in[15];
  const float* f2_w = (const float*)d_in[16]; const float* f2_b = (const float*)d_in[17];
  const float* sim_alpha = (const float*)d_in[18];
  const float* sim_beta  = (const float*)d_in[19];

  char* ws = (char*)d_ws;
  #define SLOT(i) (ws + (size_t)(i) * 16777216)
  // X transposed hi/lo
  f16* cth = (f16*)SLOT(0);
  f16* ctl = (f16*)SLOT(1);
  f16* sth = (f16*)SLOT(2);
  f16* stl = (f16*)SLOT(3);
  // prepped weights in SLOT(4)
  f16* wbase = (f16*)SLOT(4);
  f16* qw   = wbase;                 // [4][512][512]
  f16* kw   = wbase + 1 * 1048576;
  f16* q2wh = wbase + 2 * 1048576;
  f16* q2wl = wbase + 3 * 1048576;
  f16* k2wh = wbase + 4 * 1048576;
  f16* k2wl = wbase + 5 * 1048576;
  f16* vw   = wbase + 6 * 1048576;   // [1][512][512]
  f16* v2w  = vw + 262144;
  f16* f1w  = vw + 524288;
  f16* f2w  = vw + 786432;
  // conv outputs / reuse (lifetimes verified)
  f16*   q2h   = (f16*)SLOT(5);
  f16*   q2l   = (f16*)SLOT(6);
  f16*   k2h   = (f16*)SLOT(7);
  f16*   k2l   = (f16*)SLOT(0);      // after content convs
  f16*   qbuf  = (f16*)SLOT(1);      // after q2 conv
  float* pa1p  = (float*)SLOT(3);    // after k2 conv (4 MB)
  f16*   kbuf  = (f16*)SLOT(6);      // after pa1
  f16*   vbuf  = (f16*)SLOT(3);      // after pa1r
  f16*   v2buf = (f16*)SLOT(0);      // after pa1
  f16*   da_t  = (f16*)SLOT(3);      // after da1
  f16*   pa_t  = (f16*)SLOT(6);      // after da1
  // tail
  float* stats = (float*)(ws + 134217728);           // 32 KB
  float* biasp = (float*)(ws + 134217728 + 32768);   // 48 KB, overlays kagg until da1
  float* kagg  = (float*)(ws + 134217728 + 32768);   // 512 KB
  float* vagg  = (float*)(ws + 134217728 + 557056);  // 512 KB
  int*   idxb  = (int*)(ws + 134217728 + 1081344);   // 8 KB

  dim3 gconv(32, 4, 4);

  k_mvn_stats<<<4096, 256, 0, stream>>>(content, style, stats);

  // weight prep (sets: 0 q, 1 k, 2 v, 3 v2, 4 q2, 5 k2; f1/f2 plain)
  k_prep_w1<<<dim3(4,4), 256, 0, stream>>>(q_w,  q_b,  stats, 0, qw,   nullptr, biasp + 0 * 2048);
  k_prep_w1<<<dim3(4,4), 256, 0, stream>>>(k_w,  k_b,  stats, 1, kw,   nullptr, biasp + 1 * 2048);
  k_prep_w1<<<dim3(4,1), 256, 0, stream>>>(v_w,  v_b,  stats, -1, vw,  nullptr, biasp + 2 * 2048);
  k_prep_w1<<<dim3(4,1), 256, 0, stream>>>(v2_w, v2_b, stats, -1, v2w, nullptr, biasp + 3 * 2048);
  k_prep_w1<<<dim3(4,4), 256, 0, stream>>>(q2_w, q2_b, stats, 0, q2wh, q2wl,    biasp + 4 * 2048);
  k_prep_w1<<<dim3(4,4), 256, 0, stream>>>(k2_w, k2_b, stats, 1, k2wh, k2wl,    biasp + 5 * 2048);
  k_prep_w1<<<dim3(4,1), 256, 0, stream>>>(f1_w, f1_b, stats, -1, f1w, nullptr, nullptr);
  k_prep_w1<<<dim3(4,1), 256, 0, stream>>>(f2_w, f2_b, stats, -1, f2w, nullptr, nullptr);

  k_prep_x<<<dim3(32,4,2), 256, 0, stream>>>(content, style, cth, ctl, sth, stl);

  // content convs
  k_convT3<<<gconv, 256, 0, stream>>>(cth, ctl, q2wh, q2wl, biasp + 4 * 2048, q2h, q2l);
  k_convT <<<gconv, 256, 0, stream>>>(cth, qw, biasp + 0 * 2048, 1, qbuf);
  // style split conv, then PA1 (frees q2l/k2l)
  k_convT3<<<gconv, 256, 0, stream>>>(sth, stl, k2wh, k2wl, biasp + 5 * 2048, k2h, k2l);
  k_pa1<<<256, 256, 0, stream>>>(q2h, q2l, k2h, k2l, pa1p);
  k_pa1r<<<32, 64, 0, stream>>>(pa1p, idxb);
  // remaining style convs into freed slots
  k_convT<<<gconv, 256, 0, stream>>>(sth, kw,  biasp + 1 * 2048, 1, kbuf);
  k_convT<<<gconv, 256, 0, stream>>>(sth, vw,  biasp + 2 * 2048, 0, vbuf);
  k_convT<<<gconv, 256, 0, stream>>>(sth, v2w, biasp + 3 * 2048, 0, v2buf);

  k_da1<<<2048, 256, 0, stream>>>(kbuf, vbuf, sim_alpha, sim_beta, kagg, vagg);
  k_da2<<<512, 256, 0, stream>>>(qbuf, kagg, vagg, da_t);
  k_pa2<<<2048, 256, 0, stream>>>(q2h, k2h, v2buf, idxb, pa_t);

  k_finalT<<<gconv, 256, 0, stream>>>(da_t, pa_t, f1w, f2w, f1_b, f2_b,
                                      content, (float*)d_out);
}

// Round 7
// 357.586 us; speedup vs baseline: 1.5559x; 1.5559x over previous
//
#include <hip/hip_runtime.h>

typedef unsigned short u16;
typedef unsigned int   u32;
typedef _Float16       f16;

typedef f16   f16x8 __attribute__((ext_vector_type(8)));
typedef f16   f16x4 __attribute__((ext_vector_type(4)));
typedef float f32x4 __attribute__((ext_vector_type(4)));

#define LSTR 40  // LDS row stride (f16) for 128x32 GEMM tiles

__device__ __forceinline__ f32x4 mfma16(f16x8 a, f16x8 b, f32x4 c){
  return __builtin_amdgcn_mfma_f32_16x16x32_f16(a, b, c, 0, 0, 0);
}

// ============ 1. per-(b,c) spatial mean / rstd for content & style ============
__global__ __launch_bounds__(256) void k_mvn_stats(
    const float* __restrict__ content, const float* __restrict__ style,
    float* __restrict__ stats)
{
  const int src = blockIdx.x >> 11;
  const int row = blockIdx.x & 2047;
  const float* xp = (src ? style : content) + (size_t)row * 4096;
  const int t = threadIdx.x;
  double s = 0.0, ss = 0.0;
  for(int i = t * 4; i < 4096; i += 1024){
    float4 v = *(const float4*)(xp + i);
    s  += (double)v.x + (double)v.y + (double)v.z + (double)v.w;
    ss += (double)v.x * v.x + (double)v.y * v.y + (double)v.z * v.z + (double)v.w * v.w;
  }
  #pragma unroll
  for(int off = 32; off > 0; off >>= 1){
    s  += __shfl_xor(s, off);
    ss += __shfl_xor(ss, off);
  }
  __shared__ double sh[8];
  const int wid = t >> 6;
  if((t & 63) == 0){ sh[wid] = s; sh[4 + wid] = ss; }
  __syncthreads();
  if(t == 0){
    double S  = sh[0] + sh[1] + sh[2] + sh[3];
    double SS = sh[4] + sh[5] + sh[6] + sh[7];
    float mean = (float)(S * (1.0 / 4096.0));
    float var  = (float)((SS - S * S * (1.0 / 4096.0)) * (1.0 / 4095.0));
    stats[src * 4096 + row] = mean;
    stats[src * 4096 + 2048 + row] = rsqrtf(var + 1e-5f);
  }
}

// ============ 2. ALL weight preps in ONE launch: 10240 flat rows, 8 lanes/row ============
// rows: [0,2048) q | [2048,4096) k | [4096,6144) q2(hi+lo) | [6144,8192) k2(hi+lo)
//       [8192,8704) v | [8704,9216) v2 | [9216,9728) f1 | [9728,10240) f2
__global__ __launch_bounds__(256) void k_prep_w_all(
    const float* __restrict__ qW,  const float* __restrict__ qB,
    const float* __restrict__ kW,  const float* __restrict__ kB,
    const float* __restrict__ q2W, const float* __restrict__ q2B,
    const float* __restrict__ k2W, const float* __restrict__ k2B,
    const float* __restrict__ vW,  const float* __restrict__ vB,
    const float* __restrict__ v2W, const float* __restrict__ v2B,
    const float* __restrict__ f1W, const float* __restrict__ f2W,
    const float* __restrict__ stats,
    f16* __restrict__ qw, f16* __restrict__ kw,
    f16* __restrict__ q2wh, f16* __restrict__ q2wl,
    f16* __restrict__ k2wh, f16* __restrict__ k2wl,
    f16* __restrict__ vw, f16* __restrict__ v2w,
    f16* __restrict__ f1w, f16* __restrict__ f2w,
    float* __restrict__ biasp)
{
  const int t = threadIdx.x;
  int rid = blockIdx.x * 32 + (t >> 3);
  const float *W; const float *B = nullptr;
  int side = -1, b = 0, o;
  f16 *oh; f16 *ol = nullptr; float* bs = nullptr;
  if(rid < 2048){
    b = rid >> 9; o = rid & 511;
    W = qW; B = qB; side = 0;
    oh = qw + (size_t)(b * 512 + o) * 512;
    bs = biasp + 0 * 2048 + b * 512 + o;
  } else if(rid < 4096){
    rid -= 2048; b = rid >> 9; o = rid & 511;
    W = kW; B = kB; side = 1;
    oh = kw + (size_t)(b * 512 + o) * 512;
    bs = biasp + 1 * 2048 + b * 512 + o;
  } else if(rid < 6144){
    rid -= 4096; b = rid >> 9; o = rid & 511;
    W = q2W; B = q2B; side = 0;
    oh = q2wh + (size_t)(b * 512 + o) * 512;
    ol = q2wl + (size_t)(b * 512 + o) * 512;
    bs = biasp + 4 * 2048 + b * 512 + o;
  } else if(rid < 8192){
    rid -= 6144; b = rid >> 9; o = rid & 511;
    W = k2W; B = k2B; side = 1;
    oh = k2wh + (size_t)(b * 512 + o) * 512;
    ol = k2wl + (size_t)(b * 512 + o) * 512;
    bs = biasp + 5 * 2048 + b * 512 + o;
  } else if(rid < 8704){
    o = rid - 8192; W = vW; B = vB;
    oh = vw + (size_t)o * 512;
    bs = biasp + 2 * 2048 + o;
  } else if(rid < 9216){
    o = rid - 8704; W = v2W; B = v2B;
    oh = v2w + (size_t)o * 512;
    bs = biasp + 3 * 2048 + o;
  } else if(rid < 9728){
    o = rid - 9216; W = f1W;
    oh = f1w + (size_t)o * 512;
  } else {
    o = rid - 9728; W = f2W;
    oh = f2w + (size_t)o * 512;
  }
  const float* mp = (side >= 0) ? stats + side * 4096 + b * 512 : nullptr;
  const float* rp = (side >= 0) ? mp + 2048 : nullptr;
  const int c0 = (t & 7) * 64;
  float dot = 0.f;
  #pragma unroll
  for(int i = 0; i < 64; i += 8){
    int c = c0 + i;
    float w[8];
    *(float4*)(w)     = *(const float4*)(W + (size_t)o * 512 + c);
    *(float4*)(w + 4) = *(const float4*)(W + (size_t)o * 512 + c + 4);
    f16x8 h8, l8;
    #pragma unroll
    for(int j = 0; j < 8; j++){
      float wp = w[j];
      if(side >= 0){
        float r = rp[c + j];
        dot += wp * mp[c + j] * r;
        wp *= r;
      }
      f16 h = (f16)wp;
      h8[j] = h; l8[j] = (f16)(wp - (float)h);
    }
    *(f16x8*)(oh + c) = h8;
    if(ol) *(f16x8*)(ol + c) = l8;
  }
  if(bs){
    dot += __shfl_xor(dot, 1); dot += __shfl_xor(dot, 2); dot += __shfl_xor(dot, 4);
    if((t & 7) == 0) *bs = B[o] - dot;
  }
}

// ============ 3. X prep: transpose [c][s] f32 -> Xt [s][c] f16 hi+lo ============
__global__ __launch_bounds__(256) void k_prep_x(
    const float* __restrict__ content, const float* __restrict__ style,
    f16* __restrict__ cth, f16* __restrict__ ctl,
    f16* __restrict__ sth, f16* __restrict__ stl)
{
  const int side = blockIdx.z;
  const int b = blockIdx.y;
  const int s0 = blockIdx.x * 128;
  const float* Xb = (side ? style : content) + (size_t)b * 512 * 4096;
  f16* Oh = (side ? sth : cth) + (size_t)b * 4096 * 512;
  f16* Ol = (side ? stl : ctl) + (size_t)b * 4096 * 512;
  __shared__ float Xs[32][132];
  const int t = threadIdx.x;
  const int s = t >> 1, half = t & 1;
  for(int cc = 0; cc < 512; cc += 32){
    __syncthreads();
    #pragma unroll
    for(int u = 0; u < 4; u++){
      int q = t + u * 256;
      int row = q >> 5, f4 = q & 31;
      float4 v = *(const float4*)(Xb + (size_t)(cc + row) * 4096 + s0 + f4 * 4);
      *(float4*)(&Xs[row][f4 * 4]) = v;
    }
    __syncthreads();
    f16x8 h0, h1, l0, l1;
    #pragma unroll
    for(int i = 0; i < 8; i++){
      float x = Xs[half * 16 + i][s];
      f16 h = (f16)x; h0[i] = h; l0[i] = (f16)(x - (float)h);
    }
    #pragma unroll
    for(int i = 0; i < 8; i++){
      float x = Xs[half * 16 + 8 + i][s];
      f16 h = (f16)x; h1[i] = h; l1[i] = (f16)(x - (float)h);
    }
    size_t o = (size_t)(s0 + s) * 512 + cc + half * 16;
    *(f16x8*)(Oh + o) = h0; *(f16x8*)(Oh + o + 8) = h1;
    *(f16x8*)(Ol + o) = l0; *(f16x8*)(Ol + o + 8) = l1;
  }
}

// ============ 4. conv1x1 GEMM single-pass: C = W' . Xt^T + b', f16 natural out ============
__global__ __launch_bounds__(256) void k_convT(
    const f16* __restrict__ Xt, const f16* __restrict__ Wp,
    const float* __restrict__ bias, int bw, f16* __restrict__ Out)
{
  const int b = blockIdx.z;
  const int o0 = blockIdx.y * 128;
  const int s0 = blockIdx.x * 128;
  const f16* Xb = Xt + (size_t)b * 4096 * 512;
  const f16* Wb = Wp + (bw ? (size_t)b * 262144 : 0);
  const float* bp = bias + (bw ? b * 512 : 0);
  f16* Ob = Out + (size_t)b * 512 * 4096;
  __shared__ f16 As[128 * LSTR];
  __shared__ f16 Bs[128 * LSTR];
  const int t = threadIdx.x;
  const int lane = t & 63, wid = t >> 6;
  const int wm = (wid >> 1) * 64, wn = (wid & 1) * 64;
  const int lr = lane & 15, lg = lane >> 4;
  f32x4 acc[4][4] = {};
  for(int kk = 0; kk < 512; kk += 32){
    __syncthreads();
    #pragma unroll
    for(int rep = 0; rep < 2; rep++){
      int q = t + 256 * rep;
      int row = q >> 2, ch = (q & 3) * 8;
      *(f16x8*)(As + row * LSTR + ch) = *(const f16x8*)(Wb + (size_t)(o0 + row) * 512 + kk + ch);
      *(f16x8*)(Bs + row * LSTR + ch) = *(const f16x8*)(Xb + (size_t)(s0 + row) * 512 + kk + ch);
    }
    __syncthreads();
    f16x8 av[4], bv[4];
    #pragma unroll
    for(int mi = 0; mi < 4; mi++)
      av[mi] = *(const f16x8*)(As + (wm + mi * 16 + lr) * LSTR + lg * 8);
    #pragma unroll
    for(int ni = 0; ni < 4; ni++)
      bv[ni] = *(const f16x8*)(Bs + (wn + ni * 16 + lr) * LSTR + lg * 8);
    #pragma unroll
    for(int mi = 0; mi < 4; mi++){
      #pragma unroll
      for(int ni = 0; ni < 4; ni++)
        acc[mi][ni] = mfma16(av[mi], bv[ni], acc[mi][ni]);
    }
  }
  #pragma unroll
  for(int mi = 0; mi < 4; mi++){
    #pragma unroll
    for(int ni = 0; ni < 4; ni++){
      #pragma unroll
      for(int j = 0; j < 4; j++){
        int o = o0 + wm + mi * 16 + lg * 4 + j;
        int s = s0 + wn + ni * 16 + lr;
        Ob[(size_t)o * 4096 + s] = (f16)(acc[mi][ni][j] + bp[o]);
      }
    }
  }
}

// ============ 5. conv1x1 GEMM split-3 (hi/lo), hi/lo f16 natural outputs ============
__global__ __launch_bounds__(256) void k_convT3(
    const f16* __restrict__ Xh, const f16* __restrict__ Xl,
    const f16* __restrict__ Wh, const f16* __restrict__ Wl,
    const float* __restrict__ bias, f16* __restrict__ Oh, f16* __restrict__ Ol)
{
  const int b = blockIdx.z;
  const int o0 = blockIdx.y * 128;
  const int s0 = blockIdx.x * 128;
  const f16* Xhb = Xh + (size_t)b * 4096 * 512;
  const f16* Xlb = Xl + (size_t)b * 4096 * 512;
  const f16* Whb = Wh + (size_t)b * 262144;
  const f16* Wlb = Wl + (size_t)b * 262144;
  const float* bp = bias + b * 512;
  f16* Ohb = Oh + (size_t)b * 512 * 4096;
  f16* Olb = Ol + (size_t)b * 512 * 4096;
  __shared__ f16 Ah[128 * LSTR], Al[128 * LSTR], Bh[128 * LSTR], Bl[128 * LSTR];
  const int t = threadIdx.x;
  const int lane = t & 63, wid = t >> 6;
  const int wm = (wid >> 1) * 64, wn = (wid & 1) * 64;
  const int lr = lane & 15, lg = lane >> 4;
  f32x4 acc[4][4] = {};
  for(int kk = 0; kk < 512; kk += 32){
    __syncthreads();
    #pragma unroll
    for(int rep = 0; rep < 2; rep++){
      int q = t + 256 * rep;
      int row = q >> 2, ch = (q & 3) * 8;
      size_t wsrc = (size_t)(o0 + row) * 512 + kk + ch;
      size_t xsrc = (size_t)(s0 + row) * 512 + kk + ch;
      *(f16x8*)(Ah + row * LSTR + ch) = *(const f16x8*)(Whb + wsrc);
      *(f16x8*)(Al + row * LSTR + ch) = *(const f16x8*)(Wlb + wsrc);
      *(f16x8*)(Bh + row * LSTR + ch) = *(const f16x8*)(Xhb + xsrc);
      *(f16x8*)(Bl + row * LSTR + ch) = *(const f16x8*)(Xlb + xsrc);
    }
    __syncthreads();
    f16x8 ah[4], alo[4], bh[4], blo[4];
    #pragma unroll
    for(int mi = 0; mi < 4; mi++){
      ah[mi]  = *(const f16x8*)(Ah + (wm + mi * 16 + lr) * LSTR + lg * 8);
      alo[mi] = *(const f16x8*)(Al + (wm + mi * 16 + lr) * LSTR + lg * 8);
    }
    #pragma unroll
    for(int ni = 0; ni < 4; ni++){
      bh[ni]  = *(const f16x8*)(Bh + (wn + ni * 16 + lr) * LSTR + lg * 8);
      blo[ni] = *(const f16x8*)(Bl + (wn + ni * 16 + lr) * LSTR + lg * 8);
    }
    #pragma unroll
    for(int mi = 0; mi < 4; mi++){
      #pragma unroll
      for(int ni = 0; ni < 4; ni++){
        f32x4 a = acc[mi][ni];
        a = mfma16(ah[mi],  bh[ni],  a);
        a = mfma16(ah[mi],  blo[ni], a);
        a = mfma16(alo[mi], bh[ni],  a);
        acc[mi][ni] = a;
      }
    }
  }
  #pragma unroll
  for(int mi = 0; mi < 4; mi++){
    #pragma unroll
    for(int ni = 0; ni < 4; ni++){
      #pragma unroll
      for(int j = 0; j < 4; j++){
        int o = o0 + wm + mi * 16 + lg * 4 + j;
        int s = s0 + wn + ni * 16 + lr;
        float v = acc[mi][ni][j] + bp[o];
        f16 h = (f16)v;
        Ohb[(size_t)o * 4096 + s] = h;
        Olb[(size_t)o * 4096 + s] = (f16)(v - (float)h);
      }
    }
  }
}

// ============ 6. DA aggregation ============
__global__ __launch_bounds__(256) void k_da1(
    const f16* __restrict__ K, const f16* __restrict__ V,
    const float* __restrict__ alpha_p, const float* __restrict__ beta_p,
    float* __restrict__ kagg, float* __restrict__ vagg)
{
  const int x = blockIdx.x & 63, bh = blockIdx.x >> 6;
  const f16* Kb = K + (size_t)bh * 64 * 4096;
  const f16* Vb = V + (size_t)bh * 64 * 4096;
  __shared__ float kl[64][65];
  __shared__ float vl[64][65];
  __shared__ float kc[64], vc[64], simv[64];
  const int t = threadIdx.x;
  const int c = t >> 2, yp = t & 3;
  const int xb = (x >> 3) * 512 + (x & 7) * 8;
  #pragma unroll
  for(int u = 0; u < 2; u++){
    int yh = yp * 2 + u;
    f16x8 k8 = *(const f16x8*)(Kb + (size_t)c * 4096 + xb + yh * 64);
    f16x8 v8 = *(const f16x8*)(Vb + (size_t)c * 4096 + xb + yh * 64);
    #pragma unroll
    for(int j = 0; j < 8; j++){
      kl[c][yh * 8 + j] = (float)k8[j];
      vl[c][yh * 8 + j] = (float)v8[j];
    }
  }
  __syncthreads();
  float sk = 0.f, sv = 0.f;
  for(int yy = yp * 16; yy < yp * 16 + 16; yy++){ sk += kl[c][yy]; sv += vl[c][yy]; }
  sk += __shfl_xor(sk, 1); sk += __shfl_xor(sk, 2);
  sv += __shfl_xor(sv, 1); sv += __shfl_xor(sv, 2);
  if(yp == 0){ kc[c] = sk * (1.f / 64.f); vc[c] = sv * (1.f / 64.f); }
  __syncthreads();
  const int y = t >> 2, cp = t & 3;
  float d = 0.f;
  for(int cc = cp * 16; cc < cp * 16 + 16; cc++) d += kc[cc] * kl[cc][y];
  d += __shfl_xor(d, 1); d += __shfl_xor(d, 2);
  if(cp == 0) simv[y] = 1.f / (1.f + expf(-(beta_p[0] + alpha_p[0] * d)));
  __syncthreads();
  float ak = 0.f, av = 0.f;
  for(int yy = yp * 16; yy < yp * 16 + 16; yy++){
    float sm = simv[yy];
    ak += sm * kl[c][yy]; av += sm * vl[c][yy];
  }
  ak += __shfl_xor(ak, 1); ak += __shfl_xor(ak, 2);
  av += __shfl_xor(av, 1); av += __shfl_xor(av, 2);
  if(yp == 0){
    size_t o = ((size_t)bh * 64 + x) * 64 + c;
    kagg[o] = (ak + kc[c]) * (1.f / 65.f);
    vagg[o] = (av + vc[c]) * (1.f / 65.f);
  }
}

// ============ 7. DA attention MFMA; output TRANSPOSED [s][c] for final ============
__global__ __launch_bounds__(256) void k_da2(
    const f16* __restrict__ Q, const float* __restrict__ kagg,
    const float* __restrict__ vagg, f16* __restrict__ OutT)
{
  const int bh = blockIdx.x >> 4;
  const int s0 = (blockIdx.x & 15) << 8;
  const int b_ = bh >> 3, hd = bh & 7;
  const f16* Qb = Q + (size_t)bh * 64 * 4096;
  f16* Ot = OutT + (size_t)b_ * 4096 * 512 + hd * 64;

  __shared__ __align__(16) f16 Qt[256][72];
  __shared__ __align__(16) f16 Kt[64][72];
  __shared__ __align__(16) f16 Vt[64][72];
  const int t = threadIdx.x;
  const int lane = t & 63, w = t >> 6;
  const int lr = lane & 15, lg = lane >> 4;

  {
    const int so = t & 31;
    #pragma unroll
    for(int pass = 0; pass < 8; pass++){
      int c = (t >> 5) + pass * 8;
      f16x8 q8 = *(const f16x8*)(Qb + (size_t)c * 4096 + s0 + so * 8);
      #pragma unroll
      for(int j = 0; j < 8; j++){
        int s = so * 8 + j;
        int col = (((c >> 3) ^ (s & 7)) << 3) | (c & 7);
        Qt[s][col] = q8[j];
      }
    }
  }
  {
    const int z = t >> 2, c0 = (t & 3) * 16;
    #pragma unroll
    for(int u = 0; u < 4; u++){
      float4 v = *(const float4*)(kagg + (size_t)bh * 4096 + z * 64 + c0 + u * 4);
      float vv[4] = {v.x, v.y, v.z, v.w};
      #pragma unroll
      for(int j = 0; j < 4; j++){
        int c = c0 + u * 4 + j;
        int col = (((c >> 3) ^ (z & 7)) << 3) | (c & 7);
        Kt[z][col] = (f16)vv[j];
      }
    }
    #pragma unroll
    for(int u = 0; u < 4; u++){
      float4 v = *(const float4*)(vagg + (size_t)bh * 4096 + z * 64 + c0 + u * 4);
      float vv[4] = {v.x, v.y, v.z, v.w};
      #pragma unroll
      for(int j = 0; j < 4; j++){
        int c = c0 + u * 4 + j;
        int col = (((z >> 3) ^ (c & 7)) << 3) | (z & 7);
        Vt[c][col] = (f16)vv[j];
      }
    }
  }
  __syncthreads();

  f32x4 acc[4][4] = {};
  #pragma unroll
  for(int kc = 0; kc < 2; kc++){
    f16x8 af[4], bf[4];
    #pragma unroll
    for(int mi = 0; mi < 4; mi++){
      int row = w * 64 + mi * 16 + lr;
      af[mi] = *(const f16x8*)(&Qt[row][(((kc * 4 + lg) ^ (row & 7)) << 3)]);
    }
    #pragma unroll
    for(int ni = 0; ni < 4; ni++){
      int row = ni * 16 + lr;
      bf[ni] = *(const f16x8*)(&Kt[row][(((kc * 4 + lg) ^ (row & 7)) << 3)]);
    }
    #pragma unroll
    for(int mi = 0; mi < 4; mi++){
      #pragma unroll
      for(int ni = 0; ni < 4; ni++)
        acc[mi][ni] = mfma16(af[mi], bf[ni], acc[mi][ni]);
    }
  }

  #pragma unroll
  for(int mi = 0; mi < 4; mi++){
    #pragma unroll
    for(int j = 0; j < 4; j++){
      float v0 = acc[mi][0][j], v1 = acc[mi][1][j], v2 = acc[mi][2][j], v3 = acc[mi][3][j];
      float m = fmaxf(fmaxf(v0, v1), fmaxf(v2, v3));
      m = fmaxf(m, __shfl_xor(m, 1)); m = fmaxf(m, __shfl_xor(m, 2));
      m = fmaxf(m, __shfl_xor(m, 4)); m = fmaxf(m, __shfl_xor(m, 8));
      float e0 = expf(v0 - m), e1 = expf(v1 - m), e2 = expf(v2 - m), e3 = expf(v3 - m);
      float sm = e0 + e1 + e2 + e3;
      sm += __shfl_xor(sm, 1); sm += __shfl_xor(sm, 2);
      sm += __shfl_xor(sm, 4); sm += __shfl_xor(sm, 8);
      float inv = 1.f / sm;
      float ev[4] = {e0, e1, e2, e3};
      int row = w * 64 + mi * 16 + lg * 4 + j;
      #pragma unroll
      for(int ni = 0; ni < 4; ni++){
        int z = lr + 16 * ni;
        int col = (((z >> 3) ^ (row & 7)) << 3) | (z & 7);
        Qt[row][col] = (f16)(ev[ni] * inv);
      }
    }
  }
  // no barrier: each wave touches only its own Qt rows; Kt/Vt read-only

  f32x4 acc2[4][4] = {};
  #pragma unroll
  for(int kc = 0; kc < 2; kc++){
    f16x8 af[4], bf[4];
    #pragma unroll
    for(int mi = 0; mi < 4; mi++){
      int row = w * 64 + mi * 16 + lr;
      af[mi] = *(const f16x8*)(&Qt[row][(((kc * 4 + lg) ^ (row & 7)) << 3)]);
    }
    #pragma unroll
    for(int ni = 0; ni < 4; ni++){
      int row = ni * 16 + lr;
      bf[ni] = *(const f16x8*)(&Vt[row][(((kc * 4 + lg) ^ (row & 7)) << 3)]);
    }
    #pragma unroll
    for(int mi = 0; mi < 4; mi++){
      #pragma unroll
      for(int ni = 0; ni < 4; ni++)
        acc2[mi][ni] = mfma16(af[mi], bf[ni], acc2[mi][ni]);
    }
  }

  #pragma unroll
  for(int mi = 0; mi < 4; mi++){
    #pragma unroll
    for(int j = 0; j < 4; j++){
      size_t srow = (size_t)(s0 + w * 64 + mi * 16 + lg * 4 + j) * 512;
      #pragma unroll
      for(int ni = 0; ni < 4; ni++)
        Ot[srow + ni * 16 + lr] = (f16)acc2[mi][ni][j];
    }
  }
}

// ============ 8. PA1 split-K MFMA ============
__global__ __launch_bounds__(256) void k_pa1(
    const f16* __restrict__ Qh, const f16* __restrict__ Ql,
    const f16* __restrict__ Kh, const f16* __restrict__ Kl,
    float* __restrict__ pa1p)
{
  const int slice = blockIdx.x & 7;
  const int bh = blockIdx.x >> 3;
  const size_t base = (size_t)bh * 64 * 4096;
  __shared__ f16 Ah[2][64][72], Al[2][64][72], Bh[2][64][72], Bl[2][64][72];
  const int t = threadIdx.x;
  const int lane = t & 63, wid = t >> 6;
  const int wm = (wid >> 1) * 32, wn = (wid & 1) * 32;
  const int lr = lane & 15, lg = lane >> 4;
  f32x4 acc[2][2] = {};
  for(int chunk = 0; chunk < 4; chunk++){
    const int c0 = slice * 8 + chunk * 2;
    __syncthreads();
    #pragma unroll
    for(int cc = 0; cc < 2; cc++){
      size_t cbase = base + (size_t)(c0 + cc) * 4096;
      #pragma unroll
      for(int u = 0; u < 2; u++){
        int e = u * 256 + t;
        int x = e >> 3, yh = e & 7;
        size_t src = cbase + (size_t)((x >> 3) * 512 + (x & 7) * 8 + yh * 64);
        int dst = yh * 8;
        *(f16x8*)(&Ah[cc][x][dst]) = *(const f16x8*)(Qh + src);
        *(f16x8*)(&Al[cc][x][dst]) = *(const f16x8*)(Ql + src);
        *(f16x8*)(&Bh[cc][x][dst]) = *(const f16x8*)(Kh + src);
        *(f16x8*)(&Bl[cc][x][dst]) = *(const f16x8*)(Kl + src);
      }
    }
    __syncthreads();
    #pragma unroll
    for(int cc = 0; cc < 2; cc++){
      #pragma unroll
      for(int kc = 0; kc < 2; kc++){
        f16x8 ah[2], alo[2], bh[2], blo[2];
        #pragma unroll
        for(int mi = 0; mi < 2; mi++){
          ah[mi]  = *(const f16x8*)(&Ah[cc][wm + mi * 16 + lr][kc * 32 + lg * 8]);
          alo[mi] = *(const f16x8*)(&Al[cc][wm + mi * 16 + lr][kc * 32 + lg * 8]);
        }
        #pragma unroll
        for(int ni = 0; ni < 2; ni++){
          bh[ni]  = *(const f16x8*)(&Bh[cc][wn + ni * 16 + lr][kc * 32 + lg * 8]);
          blo[ni] = *(const f16x8*)(&Bl[cc][wn + ni * 16 + lr][kc * 32 + lg * 8]);
        }
        #pragma unroll
        for(int mi = 0; mi < 2; mi++){
          #pragma unroll
          for(int ni = 0; ni < 2; ni++){
            f32x4 a = acc[mi][ni];
            a = mfma16(ah[mi],  bh[ni],  a);
            a = mfma16(ah[mi],  blo[ni], a);
            a = mfma16(alo[mi], bh[ni],  a);
            acc[mi][ni] = a;
          }
        }
      }
    }
  }
  float* outp = pa1p + ((size_t)bh * 8 + slice) * 4096;
  #pragma unroll
  for(int mi = 0; mi < 2; mi++){
    #pragma unroll
    for(int ni = 0; ni < 2; ni++){
      #pragma unroll
      for(int j = 0; j < 4; j++){
        int x = wm + mi * 16 + lg * 4 + j;
        int z = wn + ni * 16 + lr;
        outp[x * 64 + z] = acc[mi][ni][j];
      }
    }
  }
}

// ============ 8b. reduce partials + argmax ============
__global__ __launch_bounds__(64) void k_pa1r(
    const float* __restrict__ pa1p, int* __restrict__ idx)
{
  const int bh = blockIdx.x;
  const int x = threadIdx.x;
  const float* p = pa1p + (size_t)bh * 8 * 4096 + x * 64;
  float best = -1e30f; int bi = 0;
  for(int z = 0; z < 64; z += 4){
    float4 v = *(const float4*)(p + z);
    #pragma unroll
    for(int sl = 1; sl < 8; sl++){
      float4 w = *(const float4*)(p + sl * 4096 + z);
      v.x += w.x; v.y += w.y; v.z += w.z; v.w += w.w;
    }
    if(v.x > best){ best = v.x; bi = z; }
    if(v.y > best){ best = v.y; bi = z + 1; }
    if(v.z > best){ best = v.z; bi = z + 2; }
    if(v.w > best){ best = v.w; bi = z + 3; }
  }
  idx[bh * 64 + x] = bi;
}

// ============ 9. PA intra-block attention; output TRANSPOSED [s][c] ============
__global__ __launch_bounds__(256) void k_pa2(
    const f16* __restrict__ Qh, const f16* __restrict__ Kh,
    const f16* __restrict__ V2, const int* __restrict__ idx, f16* __restrict__ OutT)
{
  const int hw = blockIdx.x;
  const int bh = (hw & 7) * 4 + ((hw >> 3) >> 6);
  const int x  = (hw >> 3) & 63;
  const int b_ = bh >> 3, hd = bh & 7;
  const size_t base = (size_t)bh * 64 * 4096;
  f16* Ot = OutT + (size_t)b_ * 4096 * 512 + hd * 64;

  __shared__ __align__(16) char Ubuf[18432];
  __shared__ f16 Vn[64][72];
  __shared__ f16 Ps[64][72];
  f16   (*Qt)[72] = (f16(*)[72])Ubuf;
  f16   (*Kt)[72] = (f16(*)[72])(Ubuf + 9216);
  float (*Lf)[66] = (float(*)[66])Ubuf;
  float (*Os)[67] = (float(*)[67])Ubuf;

  const int t = threadIdx.x;
  const int lane = t & 63, wid = t >> 6;
  const int wm = (wid >> 1) * 32, wn = (wid & 1) * 32;
  const int lr = lane & 15, lg = lane >> 4;

  const int xk = idx[bh * 64 + x];
  const int xb = (x >> 3) * 512 + (x & 7) * 8;
  const int kb = (xk >> 3) * 512 + (xk & 7) * 8;

  {
    const int c = t >> 2, q4 = t & 3;
    #pragma unroll
    for(int u = 0; u < 2; u++){
      int yh = q4 * 2 + u;
      f16x8 q8 = *(const f16x8*)(Qh + base + (size_t)c * 4096 + xb + yh * 64);
      f16x8 k8 = *(const f16x8*)(Kh + base + (size_t)c * 4096 + kb + yh * 64);
      f16x8 v8 = *(const f16x8*)(V2 + base + (size_t)c * 4096 + kb + yh * 64);
      int col = ((((c >> 3) ^ yh) & 7) << 3) + (c & 7);
      #pragma unroll
      for(int j = 0; j < 8; j++){
        Qt[yh * 8 + j][col] = q8[j];
        Kt[yh * 8 + j][col] = k8[j];
      }
      *(f16x8*)(&Vn[c][yh * 8]) = v8;
    }
  }
  __syncthreads();

  f32x4 acc[2][2] = {};
  #pragma unroll
  for(int kc = 0; kc < 2; kc++){
    f16x8 af[2], bf[2];
    #pragma unroll
    for(int mi = 0; mi < 2; mi++){
      int row = wm + mi * 16 + lr;
      af[mi] = *(const f16x8*)(&Qt[row][((((kc * 4 + lg) ^ (row >> 3)) & 7) << 3)]);
    }
    #pragma unroll
    for(int ni = 0; ni < 2; ni++){
      int row = wn + ni * 16 + lr;
      bf[ni] = *(const f16x8*)(&Kt[row][((((kc * 4 + lg) ^ (row >> 3)) & 7) << 3)]);
    }
    #pragma unroll
    for(int mi = 0; mi < 2; mi++){
      #pragma unroll
      for(int ni = 0; ni < 2; ni++)
        acc[mi][ni] = mfma16(af[mi], bf[ni], acc[mi][ni]);
    }
  }
  __syncthreads();
  #pragma unroll
  for(int mi = 0; mi < 2; mi++){
    #pragma unroll
    for(int ni = 0; ni < 2; ni++){
      #pragma unroll
      for(int j = 0; j < 4; j++)
        Lf[wm + mi * 16 + lg * 4 + j][wn + ni * 16 + lr] = acc[mi][ni][j];
    }
  }
  __syncthreads();

  {
    const int y = t >> 2, zp = t & 3;
    float l[16];
    #pragma unroll
    for(int i = 0; i < 16; i++) l[i] = Lf[y][zp * 16 + i];
    float m = l[0];
    #pragma unroll
    for(int i = 1; i < 16; i++) m = fmaxf(m, l[i]);
    m = fmaxf(m, __shfl_xor(m, 1)); m = fmaxf(m, __shfl_xor(m, 2));
    float sum = 0.f;
    #pragma unroll
    for(int i = 0; i < 16; i++){ l[i] = expf(l[i] - m); sum += l[i]; }
    sum += __shfl_xor(sum, 1); sum += __shfl_xor(sum, 2);
    float inv = 1.f / sum;
    f16x8 p0, p1;
    #pragma unroll
    for(int i = 0; i < 8; i++){ p0[i] = (f16)(l[i] * inv); p1[i] = (f16)(l[8 + i] * inv); }
    *(f16x8*)(&Ps[y][zp * 16]) = p0;
    *(f16x8*)(&Ps[y][zp * 16 + 8]) = p1;
  }
  __syncthreads();

  f32x4 acc2[2][2] = {};
  #pragma unroll
  for(int kc = 0; kc < 2; kc++){
    f16x8 af[2], bf[2];
    #pragma unroll
    for(int mi = 0; mi < 2; mi++)
      af[mi] = *(const f16x8*)(&Ps[wm + mi * 16 + lr][kc * 32 + lg * 8]);
    #pragma unroll
    for(int ni = 0; ni < 2; ni++)
      bf[ni] = *(const f16x8*)(&Vn[wn + ni * 16 + lr][kc * 32 + lg * 8]);
    #pragma unroll
    for(int mi = 0; mi < 2; mi++){
      #pragma unroll
      for(int ni = 0; ni < 2; ni++)
        acc2[mi][ni] = mfma16(af[mi], bf[ni], acc2[mi][ni]);
    }
  }
  #pragma unroll
  for(int mi = 0; mi < 2; mi++){
    #pragma unroll
    for(int ni = 0; ni < 2; ni++){
      #pragma unroll
      for(int j = 0; j < 4; j++)
        Os[wn + ni * 16 + lr][wm + mi * 16 + lg * 4 + j] = acc2[mi][ni][j];
    }
  }
  __syncthreads();

  {
    const int y = t >> 2, cq = (t & 3) * 16;
    size_t srow = (size_t)(xb + (y >> 3) * 64 + (y & 7)) * 512;
    f16x8 w0, w1;
    #pragma unroll
    for(int i = 0; i < 8; i++){ w0[i] = (f16)Os[cq + i][y]; w1[i] = (f16)Os[cq + 8 + i][y]; }
    *(f16x8*)(Ot + srow + cq) = w0;
    *(f16x8*)(Ot + srow + cq + 8) = w1;
  }
}

// ============ 10. Final: f1'.DA_t + f2'.PA_t + biases + content -> f32 ============
__global__ __launch_bounds__(256) void k_finalT(
    const f16* __restrict__ X1t, const f16* __restrict__ X2t,
    const f16* __restrict__ W1p, const f16* __restrict__ W2p,
    const float* __restrict__ B1, const float* __restrict__ B2,
    const float* __restrict__ content, float* __restrict__ out)
{
  const int b = blockIdx.z;
  const int o0 = blockIdx.y * 128;
  const int s0 = blockIdx.x * 128;
  __shared__ f16 As[128 * LSTR];
  __shared__ f16 Bs[128 * LSTR];
  const int t = threadIdx.x;
  const int lane = t & 63, wid = t >> 6;
  const int wm = (wid >> 1) * 64, wn = (wid & 1) * 64;
  const int lr = lane & 15, lg = lane >> 4;
  f32x4 acc[4][4] = {};
  for(int pass = 0; pass < 2; pass++){
    const f16* Xb = (pass ? X2t : X1t) + (size_t)b * 4096 * 512;
    const f16* Wb = pass ? W2p : W1p;
    for(int kk = 0; kk < 512; kk += 32){
      __syncthreads();
      #pragma unroll
      for(int rep = 0; rep < 2; rep++){
        int q = t + 256 * rep;
        int row = q >> 2, ch = (q & 3) * 8;
        *(f16x8*)(As + row * LSTR + ch) = *(const f16x8*)(Wb + (size_t)(o0 + row) * 512 + kk + ch);
        *(f16x8*)(Bs + row * LSTR + ch) = *(const f16x8*)(Xb + (size_t)(s0 + row) * 512 + kk + ch);
      }
      __syncthreads();
      f16x8 av[4], bv[4];
      #pragma unroll
      for(int mi = 0; mi < 4; mi++)
        av[mi] = *(const f16x8*)(As + (wm + mi * 16 + lr) * LSTR + lg * 8);
      #pragma unroll
      for(int ni = 0; ni < 4; ni++)
        bv[ni] = *(const f16x8*)(Bs + (wn + ni * 16 + lr) * LSTR + lg * 8);
      #pragma unroll
      for(int mi = 0; mi < 4; mi++){
        #pragma unroll
        for(int ni = 0; ni < 4; ni++)
          acc[mi][ni] = mfma16(av[mi], bv[ni], acc[mi][ni]);
      }
    }
  }
  #pragma unroll
  for(int mi = 0; mi < 4; mi++){
    #pragma unroll
    for(int ni = 0; ni < 4; ni++){
      #pragma unroll
      for(int j = 0; j < 4; j++){
        int o = o0 + wm + mi * 16 + lg * 4 + j;
        int s = s0 + wn + ni * 16 + lr;
        size_t gi = ((size_t)b * 512 + o) * 4096 + s;
        out[gi] = acc[mi][ni][j] + B1[o] + B2[o] + content[gi];
      }
    }
  }
}

extern "C" void kernel_launch(void* const* d_in, const int* in_sizes, int n_in,
                              void* d_out, int out_size, void* d_ws, size_t ws_size,
                              hipStream_t stream) {
  (void)in_sizes; (void)n_in; (void)out_size; (void)ws_size;
  const float* content = (const float*)d_in[0];
  const float* style   = (const float*)d_in[1];
  const float* q_w  = (const float*)d_in[2];  const float* q_b  = (const float*)d_in[3];
  const float* k_w  = (const float*)d_in[4];  const float* k_b  = (const float*)d_in[5];
  const float* v_w  = (const float*)d_in[6];  const float* v_b  = (const float*)d_in[7];
  const float* q2_w = (const float*)d_in[8];  const float* q2_b = (const float*)d_in[9];
  const float* k2_w = (const float*)d_in[10]; const float* k2_b = (const float*)d_in[11];
  const float* v2_w = (const float*)d_in[12]; const float* v2_b = (const float*)d_in[13];
  const float* f1_w = (const float*)d_in[14]; const float* f1_b = (const float*)d_in[15];
  const float* f2_w = (const float*)d_in[16]; const float* f2_b = (const float*)d_in[17];
  const float* sim_alpha = (const float*)d_in[18];
  const float* sim_beta  = (const float*)d_in[19];

  char* ws = (char*)d_ws;
  #define SLOT(i) (ws + (size_t)(i) * 16777216)
  f16* cth = (f16*)SLOT(0);
  f16* ctl = (f16*)SLOT(1);
  f16* sth = (f16*)SLOT(2);
  f16* stl = (f16*)SLOT(3);
  f16* wbase = (f16*)SLOT(4);
  f16* qw   = wbase;
  f16* kw   = wbase + 1 * 1048576;
  f16* q2wh = wbase + 2 * 1048576;
  f16* q2wl = wbase + 3 * 1048576;
  f16* k2wh = wbase + 4 * 1048576;
  f16* k2wl = wbase + 5 * 1048576;
  f16* vw   = wbase + 6 * 1048576;
  f16* v2w  = vw + 262144;
  f16* f1w  = vw + 524288;
  f16* f2w  = vw + 786432;
  f16*   q2h   = (f16*)SLOT(5);
  f16*   q2l   = (f16*)SLOT(6);
  f16*   k2h   = (f16*)SLOT(7);
  f16*   k2l   = (f16*)SLOT(0);      // after content convs
  f16*   qbuf  = (f16*)SLOT(1);      // after q2 conv
  float* pa1p  = (float*)SLOT(3);    // after k2 conv (4 MB)
  f16*   kbuf  = (f16*)SLOT(6);      // after pa1
  f16*   vbuf  = (f16*)SLOT(3);      // after pa1r
  f16*   v2buf = (f16*)SLOT(0);      // after pa1
  f16*   da_t  = (f16*)SLOT(3);      // after da1
  f16*   pa_t  = (f16*)SLOT(6);      // after da1
  float* stats = (float*)(ws + 134217728);
  float* biasp = (float*)(ws + 134217728 + 32768);
  float* kagg  = (float*)(ws + 134217728 + 32768);
  float* vagg  = (float*)(ws + 134217728 + 557056);
  int*   idxb  = (int*)(ws + 134217728 + 1081344);

  dim3 gconv(32, 4, 4);

  k_mvn_stats<<<4096, 256, 0, stream>>>(content, style, stats);

  // one launch for ALL weight preps (was 8 tiny latency-bound launches)
  k_prep_w_all<<<320, 256, 0, stream>>>(
      q_w, q_b, k_w, k_b, q2_w, q2_b, k2_w, k2_b,
      v_w, v_b, v2_w, v2_b, f1_w, f2_w, stats,
      qw, kw, q2wh, q2wl, k2wh, k2wl, vw, v2w, f1w, f2w, biasp);

  k_prep_x<<<dim3(32,4,2), 256, 0, stream>>>(content, style, cth, ctl, sth, stl);

  // content convs
  k_convT3<<<gconv, 256, 0, stream>>>(cth, ctl, q2wh, q2wl, biasp + 4 * 2048, q2h, q2l);
  k_convT <<<gconv, 256, 0, stream>>>(cth, qw, biasp + 0 * 2048, 1, qbuf);
  // style split conv, then PA1 (frees q2l/k2l)
  k_convT3<<<gconv, 256, 0, stream>>>(sth, stl, k2wh, k2wl, biasp + 5 * 2048, k2h, k2l);
  k_pa1<<<256, 256, 0, stream>>>(q2h, q2l, k2h, k2l, pa1p);
  k_pa1r<<<32, 64, 0, stream>>>(pa1p, idxb);
  // remaining style convs into freed slots
  k_convT<<<gconv, 256, 0, stream>>>(sth, kw,  biasp + 1 * 2048, 1, kbuf);
  k_convT<<<gconv, 256, 0, stream>>>(sth, vw,  biasp + 2 * 2048, 0, vbuf);
  k_convT<<<gconv, 256, 0, stream>>>(sth, v2w, biasp + 3 * 2048, 0, v2buf);

  k_da1<<<2048, 256, 0, stream>>>(kbuf, vbuf, sim_alpha, sim_beta, kagg, vagg);
  k_da2<<<512, 256, 0, stream>>>(qbuf, kagg, vagg, da_t);
  k_pa2<<<2048, 256, 0, stream>>>(q2h, k2h, v2buf, idxb, pa_t);

  k_finalT<<<gconv, 256, 0, stream>>>(da_t, pa_t, f1w, f2w, f1_b, f2_b,
                                      content, (float*)d_out);
}

// Round 8
// 314.421 us; speedup vs baseline: 1.7695x; 1.1373x over previous
//
#include <hip/hip_runtime.h>

typedef unsigned short u16;
typedef unsigned int   u32;
typedef _Float16       f16;

typedef f16   f16x8 __attribute__((ext_vector_type(8)));
typedef f16   f16x4 __attribute__((ext_vector_type(4)));
typedef float f32x4 __attribute__((ext_vector_type(4)));

#define LSTR 40  // LDS row stride (f16) for 128x32 GEMM tiles

__device__ __forceinline__ f32x4 mfma16(f16x8 a, f16x8 b, f32x4 c){
  return __builtin_amdgcn_mfma_f32_16x16x32_f16(a, b, c, 0, 0, 0);
}

// ============ 1. per-(b,c) spatial mean / rstd for content & style ============
__global__ __launch_bounds__(256) void k_mvn_stats(
    const float* __restrict__ content, const float* __restrict__ style,
    float* __restrict__ stats)
{
  const int src = blockIdx.x >> 11;
  const int row = blockIdx.x & 2047;
  const float* xp = (src ? style : content) + (size_t)row * 4096;
  const int t = threadIdx.x;
  double s = 0.0, ss = 0.0;
  for(int i = t * 4; i < 4096; i += 1024){
    float4 v = *(const float4*)(xp + i);
    s  += (double)v.x + (double)v.y + (double)v.z + (double)v.w;
    ss += (double)v.x * v.x + (double)v.y * v.y + (double)v.z * v.z + (double)v.w * v.w;
  }
  #pragma unroll
  for(int off = 32; off > 0; off >>= 1){
    s  += __shfl_xor(s, off);
    ss += __shfl_xor(ss, off);
  }
  __shared__ double sh[8];
  const int wid = t >> 6;
  if((t & 63) == 0){ sh[wid] = s; sh[4 + wid] = ss; }
  __syncthreads();
  if(t == 0){
    double S  = sh[0] + sh[1] + sh[2] + sh[3];
    double SS = sh[4] + sh[5] + sh[6] + sh[7];
    float mean = (float)(S * (1.0 / 4096.0));
    float var  = (float)((SS - S * S * (1.0 / 4096.0)) * (1.0 / 4095.0));
    stats[src * 4096 + row] = mean;
    stats[src * 4096 + 2048 + row] = rsqrtf(var + 1e-5f);
  }
}

// ============ 2. ALL weight preps in ONE launch: 10240 flat rows, 8 lanes/row ============
__global__ __launch_bounds__(256) void k_prep_w_all(
    const float* __restrict__ qW,  const float* __restrict__ qB,
    const float* __restrict__ kW,  const float* __restrict__ kB,
    const float* __restrict__ q2W, const float* __restrict__ q2B,
    const float* __restrict__ k2W, const float* __restrict__ k2B,
    const float* __restrict__ vW,  const float* __restrict__ vB,
    const float* __restrict__ v2W, const float* __restrict__ v2B,
    const float* __restrict__ f1W, const float* __restrict__ f2W,
    const float* __restrict__ stats,
    f16* __restrict__ qw, f16* __restrict__ kw,
    f16* __restrict__ q2wh, f16* __restrict__ q2wl,
    f16* __restrict__ k2wh, f16* __restrict__ k2wl,
    f16* __restrict__ vw, f16* __restrict__ v2w,
    f16* __restrict__ f1w, f16* __restrict__ f2w,
    float* __restrict__ biasp)
{
  const int t = threadIdx.x;
  int rid = blockIdx.x * 32 + (t >> 3);
  const float *W; const float *B = nullptr;
  int side = -1, b = 0, o;
  f16 *oh; f16 *ol = nullptr; float* bs = nullptr;
  if(rid < 2048){
    b = rid >> 9; o = rid & 511;
    W = qW; B = qB; side = 0;
    oh = qw + (size_t)(b * 512 + o) * 512;
    bs = biasp + 0 * 2048 + b * 512 + o;
  } else if(rid < 4096){
    rid -= 2048; b = rid >> 9; o = rid & 511;
    W = kW; B = kB; side = 1;
    oh = kw + (size_t)(b * 512 + o) * 512;
    bs = biasp + 1 * 2048 + b * 512 + o;
  } else if(rid < 6144){
    rid -= 4096; b = rid >> 9; o = rid & 511;
    W = q2W; B = q2B; side = 0;
    oh = q2wh + (size_t)(b * 512 + o) * 512;
    ol = q2wl + (size_t)(b * 512 + o) * 512;
    bs = biasp + 4 * 2048 + b * 512 + o;
  } else if(rid < 8192){
    rid -= 6144; b = rid >> 9; o = rid & 511;
    W = k2W; B = k2B; side = 1;
    oh = k2wh + (size_t)(b * 512 + o) * 512;
    ol = k2wl + (size_t)(b * 512 + o) * 512;
    bs = biasp + 5 * 2048 + b * 512 + o;
  } else if(rid < 8704){
    o = rid - 8192; W = vW; B = vB;
    oh = vw + (size_t)o * 512;
    bs = biasp + 2 * 2048 + o;
  } else if(rid < 9216){
    o = rid - 8704; W = v2W; B = v2B;
    oh = v2w + (size_t)o * 512;
    bs = biasp + 3 * 2048 + o;
  } else if(rid < 9728){
    o = rid - 9216; W = f1W;
    oh = f1w + (size_t)o * 512;
  } else {
    o = rid - 9728; W = f2W;
    oh = f2w + (size_t)o * 512;
  }
  const float* mp = (side >= 0) ? stats + side * 4096 + b * 512 : nullptr;
  const float* rp = (side >= 0) ? mp + 2048 : nullptr;
  const int c0 = (t & 7) * 64;
  float dot = 0.f;
  #pragma unroll
  for(int i = 0; i < 64; i += 8){
    int c = c0 + i;
    float w[8];
    *(float4*)(w)     = *(const float4*)(W + (size_t)o * 512 + c);
    *(float4*)(w + 4) = *(const float4*)(W + (size_t)o * 512 + c + 4);
    f16x8 h8, l8;
    #pragma unroll
    for(int j = 0; j < 8; j++){
      float wp = w[j];
      if(side >= 0){
        float r = rp[c + j];
        dot += wp * mp[c + j] * r;
        wp *= r;
      }
      f16 h = (f16)wp;
      h8[j] = h; l8[j] = (f16)(wp - (float)h);
    }
    *(f16x8*)(oh + c) = h8;
    if(ol) *(f16x8*)(ol + c) = l8;
  }
  if(bs){
    dot += __shfl_xor(dot, 1); dot += __shfl_xor(dot, 2); dot += __shfl_xor(dot, 4);
    if((t & 7) == 0) *bs = B[o] - dot;
  }
}

// ============ 3. X prep: transpose [c][s] f32 -> Xt [s][c] f16 hi+lo ============
__global__ __launch_bounds__(256) void k_prep_x(
    const float* __restrict__ content, const float* __restrict__ style,
    f16* __restrict__ cth, f16* __restrict__ ctl,
    f16* __restrict__ sth, f16* __restrict__ stl)
{
  const int side = blockIdx.z;
  const int b = blockIdx.y;
  const int s0 = blockIdx.x * 128;
  const float* Xb = (side ? style : content) + (size_t)b * 512 * 4096;
  f16* Oh = (side ? sth : cth) + (size_t)b * 4096 * 512;
  f16* Ol = (side ? stl : ctl) + (size_t)b * 4096 * 512;
  __shared__ float Xs[32][132];
  const int t = threadIdx.x;
  const int s = t >> 1, half = t & 1;
  for(int cc = 0; cc < 512; cc += 32){
    __syncthreads();
    #pragma unroll
    for(int u = 0; u < 4; u++){
      int q = t + u * 256;
      int row = q >> 5, f4 = q & 31;
      float4 v = *(const float4*)(Xb + (size_t)(cc + row) * 4096 + s0 + f4 * 4);
      *(float4*)(&Xs[row][f4 * 4]) = v;
    }
    __syncthreads();
    f16x8 h0, h1, l0, l1;
    #pragma unroll
    for(int i = 0; i < 8; i++){
      float x = Xs[half * 16 + i][s];
      f16 h = (f16)x; h0[i] = h; l0[i] = (f16)(x - (float)h);
    }
    #pragma unroll
    for(int i = 0; i < 8; i++){
      float x = Xs[half * 16 + 8 + i][s];
      f16 h = (f16)x; h1[i] = h; l1[i] = (f16)(x - (float)h);
    }
    size_t o = (size_t)(s0 + s) * 512 + cc + half * 16;
    *(f16x8*)(Oh + o) = h0; *(f16x8*)(Oh + o + 8) = h1;
    *(f16x8*)(Ol + o) = l0; *(f16x8*)(Ol + o + 8) = l1;
  }
}

// ============ 4. conv1x1 GEMM single-pass: C = W' . Xt^T + b', f16 natural out ============
__global__ __launch_bounds__(256) void k_convT(
    const f16* __restrict__ Xt, const f16* __restrict__ Wp,
    const float* __restrict__ bias, int bw, f16* __restrict__ Out)
{
  const int b = blockIdx.z;
  const int o0 = blockIdx.y * 128;
  const int s0 = blockIdx.x * 128;
  const f16* Xb = Xt + (size_t)b * 4096 * 512;
  const f16* Wb = Wp + (bw ? (size_t)b * 262144 : 0);
  const float* bp = bias + (bw ? b * 512 : 0);
  f16* Ob = Out + (size_t)b * 512 * 4096;
  __shared__ f16 As[128 * LSTR];
  __shared__ f16 Bs[128 * LSTR];
  const int t = threadIdx.x;
  const int lane = t & 63, wid = t >> 6;
  const int wm = (wid >> 1) * 64, wn = (wid & 1) * 64;
  const int lr = lane & 15, lg = lane >> 4;
  f32x4 acc[4][4] = {};
  for(int kk = 0; kk < 512; kk += 32){
    __syncthreads();
    #pragma unroll
    for(int rep = 0; rep < 2; rep++){
      int q = t + 256 * rep;
      int row = q >> 2, ch = (q & 3) * 8;
      *(f16x8*)(As + row * LSTR + ch) = *(const f16x8*)(Wb + (size_t)(o0 + row) * 512 + kk + ch);
      *(f16x8*)(Bs + row * LSTR + ch) = *(const f16x8*)(Xb + (size_t)(s0 + row) * 512 + kk + ch);
    }
    __syncthreads();
    f16x8 av[4], bv[4];
    #pragma unroll
    for(int mi = 0; mi < 4; mi++)
      av[mi] = *(const f16x8*)(As + (wm + mi * 16 + lr) * LSTR + lg * 8);
    #pragma unroll
    for(int ni = 0; ni < 4; ni++)
      bv[ni] = *(const f16x8*)(Bs + (wn + ni * 16 + lr) * LSTR + lg * 8);
    #pragma unroll
    for(int mi = 0; mi < 4; mi++){
      #pragma unroll
      for(int ni = 0; ni < 4; ni++)
        acc[mi][ni] = mfma16(av[mi], bv[ni], acc[mi][ni]);
    }
  }
  #pragma unroll
  for(int mi = 0; mi < 4; mi++){
    #pragma unroll
    for(int ni = 0; ni < 4; ni++){
      #pragma unroll
      for(int j = 0; j < 4; j++){
        int o = o0 + wm + mi * 16 + lg * 4 + j;
        int s = s0 + wn + ni * 16 + lr;
        Ob[(size_t)o * 4096 + s] = (f16)(acc[mi][ni][j] + bp[o]);
      }
    }
  }
}

// ============ 4b. fused 3-output style conv: k (batched W), v, v2 in one launch ============
__global__ __launch_bounds__(256) void k_conv3out(
    const f16* __restrict__ Xt,
    const f16* __restrict__ Wk, const f16* __restrict__ Wv, const f16* __restrict__ Wv2,
    const float* __restrict__ biasp,
    f16* __restrict__ Ok, f16* __restrict__ Ov, f16* __restrict__ Ov2)
{
  const int b = blockIdx.z;
  const int seg = blockIdx.y >> 2;             // 0=k 1=v 2=v2
  const int o0 = (blockIdx.y & 3) * 128;
  const int s0 = blockIdx.x * 128;
  const f16* Xb = Xt + (size_t)b * 4096 * 512;
  const f16* Wb = seg == 0 ? Wk + (size_t)b * 262144 : (seg == 1 ? Wv : Wv2);
  const float* bp = biasp + (seg == 0 ? 1 * 2048 + b * 512 : (seg == 1 ? 2 * 2048 : 3 * 2048));
  f16* Ob = (seg == 0 ? Ok : (seg == 1 ? Ov : Ov2)) + (size_t)b * 512 * 4096;
  __shared__ f16 As[128 * LSTR];
  __shared__ f16 Bs[128 * LSTR];
  const int t = threadIdx.x;
  const int lane = t & 63, wid = t >> 6;
  const int wm = (wid >> 1) * 64, wn = (wid & 1) * 64;
  const int lr = lane & 15, lg = lane >> 4;
  f32x4 acc[4][4] = {};
  for(int kk = 0; kk < 512; kk += 32){
    __syncthreads();
    #pragma unroll
    for(int rep = 0; rep < 2; rep++){
      int q = t + 256 * rep;
      int row = q >> 2, ch = (q & 3) * 8;
      *(f16x8*)(As + row * LSTR + ch) = *(const f16x8*)(Wb + (size_t)(o0 + row) * 512 + kk + ch);
      *(f16x8*)(Bs + row * LSTR + ch) = *(const f16x8*)(Xb + (size_t)(s0 + row) * 512 + kk + ch);
    }
    __syncthreads();
    f16x8 av[4], bv[4];
    #pragma unroll
    for(int mi = 0; mi < 4; mi++)
      av[mi] = *(const f16x8*)(As + (wm + mi * 16 + lr) * LSTR + lg * 8);
    #pragma unroll
    for(int ni = 0; ni < 4; ni++)
      bv[ni] = *(const f16x8*)(Bs + (wn + ni * 16 + lr) * LSTR + lg * 8);
    #pragma unroll
    for(int mi = 0; mi < 4; mi++){
      #pragma unroll
      for(int ni = 0; ni < 4; ni++)
        acc[mi][ni] = mfma16(av[mi], bv[ni], acc[mi][ni]);
    }
  }
  #pragma unroll
  for(int mi = 0; mi < 4; mi++){
    #pragma unroll
    for(int ni = 0; ni < 4; ni++){
      #pragma unroll
      for(int j = 0; j < 4; j++){
        int o = o0 + wm + mi * 16 + lg * 4 + j;
        int s = s0 + wn + ni * 16 + lr;
        Ob[(size_t)o * 4096 + s] = (f16)(acc[mi][ni][j] + bp[o]);
      }
    }
  }
}

// ============ 5. conv1x1 GEMM split-3 (hi/lo), hi/lo f16 natural outputs ============
__global__ __launch_bounds__(256) void k_convT3(
    const f16* __restrict__ Xh, const f16* __restrict__ Xl,
    const f16* __restrict__ Wh, const f16* __restrict__ Wl,
    const float* __restrict__ bias, f16* __restrict__ Oh, f16* __restrict__ Ol)
{
  const int b = blockIdx.z;
  const int o0 = blockIdx.y * 128;
  const int s0 = blockIdx.x * 128;
  const f16* Xhb = Xh + (size_t)b * 4096 * 512;
  const f16* Xlb = Xl + (size_t)b * 4096 * 512;
  const f16* Whb = Wh + (size_t)b * 262144;
  const f16* Wlb = Wl + (size_t)b * 262144;
  const float* bp = bias + b * 512;
  f16* Ohb = Oh + (size_t)b * 512 * 4096;
  f16* Olb = Ol + (size_t)b * 512 * 4096;
  __shared__ f16 Ah[128 * LSTR], Al[128 * LSTR], Bh[128 * LSTR], Bl[128 * LSTR];
  const int t = threadIdx.x;
  const int lane = t & 63, wid = t >> 6;
  const int wm = (wid >> 1) * 64, wn = (wid & 1) * 64;
  const int lr = lane & 15, lg = lane >> 4;
  f32x4 acc[4][4] = {};
  for(int kk = 0; kk < 512; kk += 32){
    __syncthreads();
    #pragma unroll
    for(int rep = 0; rep < 2; rep++){
      int q = t + 256 * rep;
      int row = q >> 2, ch = (q & 3) * 8;
      size_t wsrc = (size_t)(o0 + row) * 512 + kk + ch;
      size_t xsrc = (size_t)(s0 + row) * 512 + kk + ch;
      *(f16x8*)(Ah + row * LSTR + ch) = *(const f16x8*)(Whb + wsrc);
      *(f16x8*)(Al + row * LSTR + ch) = *(const f16x8*)(Wlb + wsrc);
      *(f16x8*)(Bh + row * LSTR + ch) = *(const f16x8*)(Xhb + xsrc);
      *(f16x8*)(Bl + row * LSTR + ch) = *(const f16x8*)(Xlb + xsrc);
    }
    __syncthreads();
    f16x8 ah[4], alo[4], bh[4], blo[4];
    #pragma unroll
    for(int mi = 0; mi < 4; mi++){
      ah[mi]  = *(const f16x8*)(Ah + (wm + mi * 16 + lr) * LSTR + lg * 8);
      alo[mi] = *(const f16x8*)(Al + (wm + mi * 16 + lr) * LSTR + lg * 8);
    }
    #pragma unroll
    for(int ni = 0; ni < 4; ni++){
      bh[ni]  = *(const f16x8*)(Bh + (wn + ni * 16 + lr) * LSTR + lg * 8);
      blo[ni] = *(const f16x8*)(Bl + (wn + ni * 16 + lr) * LSTR + lg * 8);
    }
    #pragma unroll
    for(int mi = 0; mi < 4; mi++){
      #pragma unroll
      for(int ni = 0; ni < 4; ni++){
        f32x4 a = acc[mi][ni];
        a = mfma16(ah[mi],  bh[ni],  a);
        a = mfma16(ah[mi],  blo[ni], a);
        a = mfma16(alo[mi], bh[ni],  a);
        acc[mi][ni] = a;
      }
    }
  }
  #pragma unroll
  for(int mi = 0; mi < 4; mi++){
    #pragma unroll
    for(int ni = 0; ni < 4; ni++){
      #pragma unroll
      for(int j = 0; j < 4; j++){
        int o = o0 + wm + mi * 16 + lg * 4 + j;
        int s = s0 + wn + ni * 16 + lr;
        float v = acc[mi][ni][j] + bp[o];
        f16 h = (f16)v;
        Ohb[(size_t)o * 4096 + s] = h;
        Olb[(size_t)o * 4096 + s] = (f16)(v - (float)h);
      }
    }
  }
}

// ============ 6. DA aggregation — XCD-grouped so line-sharing siblings colocate ============
__global__ __launch_bounds__(256) void k_da1(
    const f16* __restrict__ K, const f16* __restrict__ V,
    const float* __restrict__ alpha_p, const float* __restrict__ beta_p,
    float* __restrict__ kagg, float* __restrict__ vagg)
{
  // blocks with same (bh, x>>3) share cache lines; give them equal hw&7 (same XCD)
  const int hw = blockIdx.x;
  const int xcd = hw & 7, i = hw >> 3;
  const int g = xcd * 32 + (i >> 3);      // group: 32 bh x 8 xo = 256 groups
  const int bh = g >> 3;
  const int x  = (g & 7) * 8 + (i & 7);
  const f16* Kb = K + (size_t)bh * 64 * 4096;
  const f16* Vb = V + (size_t)bh * 64 * 4096;
  __shared__ float kl[64][65];
  __shared__ float vl[64][65];
  __shared__ float kc[64], vc[64], simv[64];
  const int t = threadIdx.x;
  const int c = t >> 2, yp = t & 3;
  const int xb = (x >> 3) * 512 + (x & 7) * 8;
  #pragma unroll
  for(int u = 0; u < 2; u++){
    int yh = yp * 2 + u;
    f16x8 k8 = *(const f16x8*)(Kb + (size_t)c * 4096 + xb + yh * 64);
    f16x8 v8 = *(const f16x8*)(Vb + (size_t)c * 4096 + xb + yh * 64);
    #pragma unroll
    for(int j = 0; j < 8; j++){
      kl[c][yh * 8 + j] = (float)k8[j];
      vl[c][yh * 8 + j] = (float)v8[j];
    }
  }
  __syncthreads();
  float sk = 0.f, sv = 0.f;
  for(int yy = yp * 16; yy < yp * 16 + 16; yy++){ sk += kl[c][yy]; sv += vl[c][yy]; }
  sk += __shfl_xor(sk, 1); sk += __shfl_xor(sk, 2);
  sv += __shfl_xor(sv, 1); sv += __shfl_xor(sv, 2);
  if(yp == 0){ kc[c] = sk * (1.f / 64.f); vc[c] = sv * (1.f / 64.f); }
  __syncthreads();
  const int y = t >> 2, cp = t & 3;
  float d = 0.f;
  for(int cc = cp * 16; cc < cp * 16 + 16; cc++) d += kc[cc] * kl[cc][y];
  d += __shfl_xor(d, 1); d += __shfl_xor(d, 2);
  if(cp == 0) simv[y] = 1.f / (1.f + expf(-(beta_p[0] + alpha_p[0] * d)));
  __syncthreads();
  float ak = 0.f, av = 0.f;
  for(int yy = yp * 16; yy < yp * 16 + 16; yy++){
    float sm = simv[yy];
    ak += sm * kl[c][yy]; av += sm * vl[c][yy];
  }
  ak += __shfl_xor(ak, 1); ak += __shfl_xor(ak, 2);
  av += __shfl_xor(av, 1); av += __shfl_xor(av, 2);
  if(yp == 0){
    size_t o = ((size_t)bh * 64 + x) * 64 + c;
    kagg[o] = (ak + kc[c]) * (1.f / 65.f);
    vagg[o] = (av + vc[c]) * (1.f / 65.f);
  }
}

// ============ 7. DA attention MFMA; output TRANSPOSED [s][c] for final ============
__global__ __launch_bounds__(256) void k_da2(
    const f16* __restrict__ Q, const float* __restrict__ kagg,
    const float* __restrict__ vagg, f16* __restrict__ OutT)
{
  const int bh = blockIdx.x >> 4;
  const int s0 = (blockIdx.x & 15) << 8;
  const int b_ = bh >> 3, hd = bh & 7;
  const f16* Qb = Q + (size_t)bh * 64 * 4096;
  f16* Ot = OutT + (size_t)b_ * 4096 * 512 + hd * 64;

  __shared__ __align__(16) f16 Qt[256][72];
  __shared__ __align__(16) f16 Kt[64][72];
  __shared__ __align__(16) f16 Vt[64][72];
  const int t = threadIdx.x;
  const int lane = t & 63, w = t >> 6;
  const int lr = lane & 15, lg = lane >> 4;

  {
    const int so = t & 31;
    #pragma unroll
    for(int pass = 0; pass < 8; pass++){
      int c = (t >> 5) + pass * 8;
      f16x8 q8 = *(const f16x8*)(Qb + (size_t)c * 4096 + s0 + so * 8);
      #pragma unroll
      for(int j = 0; j < 8; j++){
        int s = so * 8 + j;
        int col = (((c >> 3) ^ (s & 7)) << 3) | (c & 7);
        Qt[s][col] = q8[j];
      }
    }
  }
  {
    const int z = t >> 2, c0 = (t & 3) * 16;
    #pragma unroll
    for(int u = 0; u < 4; u++){
      float4 v = *(const float4*)(kagg + (size_t)bh * 4096 + z * 64 + c0 + u * 4);
      float vv[4] = {v.x, v.y, v.z, v.w};
      #pragma unroll
      for(int j = 0; j < 4; j++){
        int c = c0 + u * 4 + j;
        int col = (((c >> 3) ^ (z & 7)) << 3) | (c & 7);
        Kt[z][col] = (f16)vv[j];
      }
    }
    #pragma unroll
    for(int u = 0; u < 4; u++){
      float4 v = *(const float4*)(vagg + (size_t)bh * 4096 + z * 64 + c0 + u * 4);
      float vv[4] = {v.x, v.y, v.z, v.w};
      #pragma unroll
      for(int j = 0; j < 4; j++){
        int c = c0 + u * 4 + j;
        int col = (((z >> 3) ^ (c & 7)) << 3) | (z & 7);
        Vt[c][col] = (f16)vv[j];
      }
    }
  }
  __syncthreads();

  f32x4 acc[4][4] = {};
  #pragma unroll
  for(int kc = 0; kc < 2; kc++){
    f16x8 af[4], bf[4];
    #pragma unroll
    for(int mi = 0; mi < 4; mi++){
      int row = w * 64 + mi * 16 + lr;
      af[mi] = *(const f16x8*)(&Qt[row][(((kc * 4 + lg) ^ (row & 7)) << 3)]);
    }
    #pragma unroll
    for(int ni = 0; ni < 4; ni++){
      int row = ni * 16 + lr;
      bf[ni] = *(const f16x8*)(&Kt[row][(((kc * 4 + lg) ^ (row & 7)) << 3)]);
    }
    #pragma unroll
    for(int mi = 0; mi < 4; mi++){
      #pragma unroll
      for(int ni = 0; ni < 4; ni++)
        acc[mi][ni] = mfma16(af[mi], bf[ni], acc[mi][ni]);
    }
  }

  #pragma unroll
  for(int mi = 0; mi < 4; mi++){
    #pragma unroll
    for(int j = 0; j < 4; j++){
      float v0 = acc[mi][0][j], v1 = acc[mi][1][j], v2 = acc[mi][2][j], v3 = acc[mi][3][j];
      float m = fmaxf(fmaxf(v0, v1), fmaxf(v2, v3));
      m = fmaxf(m, __shfl_xor(m, 1)); m = fmaxf(m, __shfl_xor(m, 2));
      m = fmaxf(m, __shfl_xor(m, 4)); m = fmaxf(m, __shfl_xor(m, 8));
      float e0 = expf(v0 - m), e1 = expf(v1 - m), e2 = expf(v2 - m), e3 = expf(v3 - m);
      float sm = e0 + e1 + e2 + e3;
      sm += __shfl_xor(sm, 1); sm += __shfl_xor(sm, 2);
      sm += __shfl_xor(sm, 4); sm += __shfl_xor(sm, 8);
      float inv = 1.f / sm;
      float ev[4] = {e0, e1, e2, e3};
      int row = w * 64 + mi * 16 + lg * 4 + j;
      #pragma unroll
      for(int ni = 0; ni < 4; ni++){
        int z = lr + 16 * ni;
        int col = (((z >> 3) ^ (row & 7)) << 3) | (z & 7);
        Qt[row][col] = (f16)(ev[ni] * inv);
      }
    }
  }
  // no barrier: each wave touches only its own Qt rows; Kt/Vt read-only

  f32x4 acc2[4][4] = {};
  #pragma unroll
  for(int kc = 0; kc < 2; kc++){
    f16x8 af[4], bf[4];
    #pragma unroll
    for(int mi = 0; mi < 4; mi++){
      int row = w * 64 + mi * 16 + lr;
      af[mi] = *(const f16x8*)(&Qt[row][(((kc * 4 + lg) ^ (row & 7)) << 3)]);
    }
    #pragma unroll
    for(int ni = 0; ni < 4; ni++){
      int row = ni * 16 + lr;
      bf[ni] = *(const f16x8*)(&Vt[row][(((kc * 4 + lg) ^ (row & 7)) << 3)]);
    }
    #pragma unroll
    for(int mi = 0; mi < 4; mi++){
      #pragma unroll
      for(int ni = 0; ni < 4; ni++)
        acc2[mi][ni] = mfma16(af[mi], bf[ni], acc2[mi][ni]);
    }
  }

  #pragma unroll
  for(int mi = 0; mi < 4; mi++){
    #pragma unroll
    for(int j = 0; j < 4; j++){
      size_t srow = (size_t)(s0 + w * 64 + mi * 16 + lg * 4 + j) * 512;
      #pragma unroll
      for(int ni = 0; ni < 4; ni++)
        Ot[srow + ni * 16 + lr] = (f16)acc2[mi][ni][j];
    }
  }
}

// ============ 8. PA1 split-K MFMA ============
__global__ __launch_bounds__(256) void k_pa1(
    const f16* __restrict__ Qh, const f16* __restrict__ Ql,
    const f16* __restrict__ Kh, const f16* __restrict__ Kl,
    float* __restrict__ pa1p)
{
  const int slice = blockIdx.x & 7;
  const int bh = blockIdx.x >> 3;
  const size_t base = (size_t)bh * 64 * 4096;
  __shared__ f16 Ah[2][64][72], Al[2][64][72], Bh[2][64][72], Bl[2][64][72];
  const int t = threadIdx.x;
  const int lane = t & 63, wid = t >> 6;
  const int wm = (wid >> 1) * 32, wn = (wid & 1) * 32;
  const int lr = lane & 15, lg = lane >> 4;
  f32x4 acc[2][2] = {};
  for(int chunk = 0; chunk < 4; chunk++){
    const int c0 = slice * 8 + chunk * 2;
    __syncthreads();
    #pragma unroll
    for(int cc = 0; cc < 2; cc++){
      size_t cbase = base + (size_t)(c0 + cc) * 4096;
      #pragma unroll
      for(int u = 0; u < 2; u++){
        int e = u * 256 + t;
        int x = e >> 3, yh = e & 7;
        size_t src = cbase + (size_t)((x >> 3) * 512 + (x & 7) * 8 + yh * 64);
        int dst = yh * 8;
        *(f16x8*)(&Ah[cc][x][dst]) = *(const f16x8*)(Qh + src);
        *(f16x8*)(&Al[cc][x][dst]) = *(const f16x8*)(Ql + src);
        *(f16x8*)(&Bh[cc][x][dst]) = *(const f16x8*)(Kh + src);
        *(f16x8*)(&Bl[cc][x][dst]) = *(const f16x8*)(Kl + src);
      }
    }
    __syncthreads();
    #pragma unroll
    for(int cc = 0; cc < 2; cc++){
      #pragma unroll
      for(int kc = 0; kc < 2; kc++){
        f16x8 ah[2], alo[2], bh[2], blo[2];
        #pragma unroll
        for(int mi = 0; mi < 2; mi++){
          ah[mi]  = *(const f16x8*)(&Ah[cc][wm + mi * 16 + lr][kc * 32 + lg * 8]);
          alo[mi] = *(const f16x8*)(&Al[cc][wm + mi * 16 + lr][kc * 32 + lg * 8]);
        }
        #pragma unroll
        for(int ni = 0; ni < 2; ni++){
          bh[ni]  = *(const f16x8*)(&Bh[cc][wn + ni * 16 + lr][kc * 32 + lg * 8]);
          blo[ni] = *(const f16x8*)(&Bl[cc][wn + ni * 16 + lr][kc * 32 + lg * 8]);
        }
        #pragma unroll
        for(int mi = 0; mi < 2; mi++){
          #pragma unroll
          for(int ni = 0; ni < 2; ni++){
            f32x4 a = acc[mi][ni];
            a = mfma16(ah[mi],  bh[ni],  a);
            a = mfma16(ah[mi],  blo[ni], a);
            a = mfma16(alo[mi], bh[ni],  a);
            acc[mi][ni] = a;
          }
        }
      }
    }
  }
  float* outp = pa1p + ((size_t)bh * 8 + slice) * 4096;
  #pragma unroll
  for(int mi = 0; mi < 2; mi++){
    #pragma unroll
    for(int ni = 0; ni < 2; ni++){
      #pragma unroll
      for(int j = 0; j < 4; j++){
        int x = wm + mi * 16 + lg * 4 + j;
        int z = wn + ni * 16 + lr;
        outp[x * 64 + z] = acc[mi][ni][j];
      }
    }
  }
}

// ============ 8b. reduce partials + argmax ============
__global__ __launch_bounds__(64) void k_pa1r(
    const float* __restrict__ pa1p, int* __restrict__ idx)
{
  const int bh = blockIdx.x;
  const int x = threadIdx.x;
  const float* p = pa1p + (size_t)bh * 8 * 4096 + x * 64;
  float best = -1e30f; int bi = 0;
  for(int z = 0; z < 64; z += 4){
    float4 v = *(const float4*)(p + z);
    #pragma unroll
    for(int sl = 1; sl < 8; sl++){
      float4 w = *(const float4*)(p + sl * 4096 + z);
      v.x += w.x; v.y += w.y; v.z += w.z; v.w += w.w;
    }
    if(v.x > best){ best = v.x; bi = z; }
    if(v.y > best){ best = v.y; bi = z + 1; }
    if(v.z > best){ best = v.z; bi = z + 2; }
    if(v.w > best){ best = v.w; bi = z + 3; }
  }
  idx[bh * 64 + x] = bi;
}

// ============ 9. PA intra-block attention; output TRANSPOSED [s][c] ============
__global__ __launch_bounds__(256) void k_pa2(
    const f16* __restrict__ Qh, const f16* __restrict__ Kh,
    const f16* __restrict__ V2, const int* __restrict__ idx, f16* __restrict__ OutT)
{
  const int hw = blockIdx.x;
  const int bh = (hw & 7) * 4 + ((hw >> 3) >> 6);
  const int x  = (hw >> 3) & 63;
  const int b_ = bh >> 3, hd = bh & 7;
  const size_t base = (size_t)bh * 64 * 4096;
  f16* Ot = OutT + (size_t)b_ * 4096 * 512 + hd * 64;

  __shared__ __align__(16) char Ubuf[18432];
  __shared__ f16 Vn[64][72];
  __shared__ f16 Ps[64][72];
  f16   (*Qt)[72] = (f16(*)[72])Ubuf;
  f16   (*Kt)[72] = (f16(*)[72])(Ubuf + 9216);
  float (*Lf)[66] = (float(*)[66])Ubuf;
  float (*Os)[67] = (float(*)[67])Ubuf;

  const int t = threadIdx.x;
  const int lane = t & 63, wid = t >> 6;
  const int wm = (wid >> 1) * 32, wn = (wid & 1) * 32;
  const int lr = lane & 15, lg = lane >> 4;

  const int xk = idx[bh * 64 + x];
  const int xb = (x >> 3) * 512 + (x & 7) * 8;
  const int kb = (xk >> 3) * 512 + (xk & 7) * 8;

  {
    const int c = t >> 2, q4 = t & 3;
    #pragma unroll
    for(int u = 0; u < 2; u++){
      int yh = q4 * 2 + u;
      f16x8 q8 = *(const f16x8*)(Qh + base + (size_t)c * 4096 + xb + yh * 64);
      f16x8 k8 = *(const f16x8*)(Kh + base + (size_t)c * 4096 + kb + yh * 64);
      f16x8 v8 = *(const f16x8*)(V2 + base + (size_t)c * 4096 + kb + yh * 64);
      int col = ((((c >> 3) ^ yh) & 7) << 3) + (c & 7);
      #pragma unroll
      for(int j = 0; j < 8; j++){
        Qt[yh * 8 + j][col] = q8[j];
        Kt[yh * 8 + j][col] = k8[j];
      }
      *(f16x8*)(&Vn[c][yh * 8]) = v8;
    }
  }
  __syncthreads();

  f32x4 acc[2][2] = {};
  #pragma unroll
  for(int kc = 0; kc < 2; kc++){
    f16x8 af[2], bf[2];
    #pragma unroll
    for(int mi = 0; mi < 2; mi++){
      int row = wm + mi * 16 + lr;
      af[mi] = *(const f16x8*)(&Qt[row][((((kc * 4 + lg) ^ (row >> 3)) & 7) << 3)]);
    }
    #pragma unroll
    for(int ni = 0; ni < 2; ni++){
      int row = wn + ni * 16 + lr;
      bf[ni] = *(const f16x8*)(&Kt[row][((((kc * 4 + lg) ^ (row >> 3)) & 7) << 3)]);
    }
    #pragma unroll
    for(int mi = 0; mi < 2; mi++){
      #pragma unroll
      for(int ni = 0; ni < 2; ni++)
        acc[mi][ni] = mfma16(af[mi], bf[ni], acc[mi][ni]);
    }
  }
  __syncthreads();
  #pragma unroll
  for(int mi = 0; mi < 2; mi++){
    #pragma unroll
    for(int ni = 0; ni < 2; ni++){
      #pragma unroll
      for(int j = 0; j < 4; j++)
        Lf[wm + mi * 16 + lg * 4 + j][wn + ni * 16 + lr] = acc[mi][ni][j];
    }
  }
  __syncthreads();

  {
    const int y = t >> 2, zp = t & 3;
    float l[16];
    #pragma unroll
    for(int i = 0; i < 16; i++) l[i] = Lf[y][zp * 16 + i];
    float m = l[0];
    #pragma unroll
    for(int i = 1; i < 16; i++) m = fmaxf(m, l[i]);
    m = fmaxf(m, __shfl_xor(m, 1)); m = fmaxf(m, __shfl_xor(m, 2));
    float sum = 0.f;
    #pragma unroll
    for(int i = 0; i < 16; i++){ l[i] = expf(l[i] - m); sum += l[i]; }
    sum += __shfl_xor(sum, 1); sum += __shfl_xor(sum, 2);
    float inv = 1.f / sum;
    f16x8 p0, p1;
    #pragma unroll
    for(int i = 0; i < 8; i++){ p0[i] = (f16)(l[i] * inv); p1[i] = (f16)(l[8 + i] * inv); }
    *(f16x8*)(&Ps[y][zp * 16]) = p0;
    *(f16x8*)(&Ps[y][zp * 16 + 8]) = p1;
  }
  __syncthreads();

  f32x4 acc2[2][2] = {};
  #pragma unroll
  for(int kc = 0; kc < 2; kc++){
    f16x8 af[2], bf[2];
    #pragma unroll
    for(int mi = 0; mi < 2; mi++)
      af[mi] = *(const f16x8*)(&Ps[wm + mi * 16 + lr][kc * 32 + lg * 8]);
    #pragma unroll
    for(int ni = 0; ni < 2; ni++)
      bf[ni] = *(const f16x8*)(&Vn[wn + ni * 16 + lr][kc * 32 + lg * 8]);
    #pragma unroll
    for(int mi = 0; mi < 2; mi++){
      #pragma unroll
      for(int ni = 0; ni < 2; ni++)
        acc2[mi][ni] = mfma16(af[mi], bf[ni], acc2[mi][ni]);
    }
  }
  #pragma unroll
  for(int mi = 0; mi < 2; mi++){
    #pragma unroll
    for(int ni = 0; ni < 2; ni++){
      #pragma unroll
      for(int j = 0; j < 4; j++)
        Os[wn + ni * 16 + lr][wm + mi * 16 + lg * 4 + j] = acc2[mi][ni][j];
    }
  }
  __syncthreads();

  {
    const int y = t >> 2, cq = (t & 3) * 16;
    size_t srow = (size_t)(xb + (y >> 3) * 64 + (y & 7)) * 512;
    f16x8 w0, w1;
    #pragma unroll
    for(int i = 0; i < 8; i++){ w0[i] = (f16)Os[cq + i][y]; w1[i] = (f16)Os[cq + 8 + i][y]; }
    *(f16x8*)(Ot + srow + cq) = w0;
    *(f16x8*)(Ot + srow + cq + 8) = w1;
  }
}

// ============ 10. Final: f1'.DA_t + f2'.PA_t + biases + content -> f32 ============
__global__ __launch_bounds__(256) void k_finalT(
    const f16* __restrict__ X1t, const f16* __restrict__ X2t,
    const f16* __restrict__ W1p, const f16* __restrict__ W2p,
    const float* __restrict__ B1, const float* __restrict__ B2,
    const float* __restrict__ content, float* __restrict__ out)
{
  const int b = blockIdx.z;
  const int o0 = blockIdx.y * 128;
  const int s0 = blockIdx.x * 128;
  __shared__ f16 As[128 * LSTR];
  __shared__ f16 Bs[128 * LSTR];
  const int t = threadIdx.x;
  const int lane = t & 63, wid = t >> 6;
  const int wm = (wid >> 1) * 64, wn = (wid & 1) * 64;
  const int lr = lane & 15, lg = lane >> 4;
  f32x4 acc[4][4] = {};
  for(int pass = 0; pass < 2; pass++){
    const f16* Xb = (pass ? X2t : X1t) + (size_t)b * 4096 * 512;
    const f16* Wb = pass ? W2p : W1p;
    for(int kk = 0; kk < 512; kk += 32){
      __syncthreads();
      #pragma unroll
      for(int rep = 0; rep < 2; rep++){
        int q = t + 256 * rep;
        int row = q >> 2, ch = (q & 3) * 8;
        *(f16x8*)(As + row * LSTR + ch) = *(const f16x8*)(Wb + (size_t)(o0 + row) * 512 + kk + ch);
        *(f16x8*)(Bs + row * LSTR + ch) = *(const f16x8*)(Xb + (size_t)(s0 + row) * 512 + kk + ch);
      }
      __syncthreads();
      f16x8 av[4], bv[4];
      #pragma unroll
      for(int mi = 0; mi < 4; mi++)
        av[mi] = *(const f16x8*)(As + (wm + mi * 16 + lr) * LSTR + lg * 8);
      #pragma unroll
      for(int ni = 0; ni < 4; ni++)
        bv[ni] = *(const f16x8*)(Bs + (wn + ni * 16 + lr) * LSTR + lg * 8);
      #pragma unroll
      for(int mi = 0; mi < 4; mi++){
        #pragma unroll
        for(int ni = 0; ni < 4; ni++)
          acc[mi][ni] = mfma16(av[mi], bv[ni], acc[mi][ni]);
      }
    }
  }
  #pragma unroll
  for(int mi = 0; mi < 4; mi++){
    #pragma unroll
    for(int ni = 0; ni < 4; ni++){
      #pragma unroll
      for(int j = 0; j < 4; j++){
        int o = o0 + wm + mi * 16 + lg * 4 + j;
        int s = s0 + wn + ni * 16 + lr;
        size_t gi = ((size_t)b * 512 + o) * 4096 + s;
        out[gi] = acc[mi][ni][j] + B1[o] + B2[o] + content[gi];
      }
    }
  }
}

extern "C" void kernel_launch(void* const* d_in, const int* in_sizes, int n_in,
                              void* d_out, int out_size, void* d_ws, size_t ws_size,
                              hipStream_t stream) {
  (void)in_sizes; (void)n_in; (void)out_size; (void)ws_size;
  const float* content = (const float*)d_in[0];
  const float* style   = (const float*)d_in[1];
  const float* q_w  = (const float*)d_in[2];  const float* q_b  = (const float*)d_in[3];
  const float* k_w  = (const float*)d_in[4];  const float* k_b  = (const float*)d_in[5];
  const float* v_w  = (const float*)d_in[6];  const float* v_b  = (const float*)d_in[7];
  const float* q2_w = (const float*)d_in[8];  const float* q2_b = (const float*)d_in[9];
  const float* k2_w = (const float*)d_in[10]; const float* k2_b = (const float*)d_in[11];
  const float* v2_w = (const float*)d_in[12]; const float* v2_b = (const float*)d_in[13];
  const float* f1_w = (const float*)d_in[14]; const float* f1_b = (const float*)d_in[15];
  const float* f2_w = (const float*)d_in[16]; const float* f2_b = (const float*)d_in[17];
  const float* sim_alpha = (const float*)d_in[18];
  const float* sim_beta  = (const float*)d_in[19];

  char* ws = (char*)d_ws;
  #define SLOT(i) (ws + (size_t)(i) * 16777216)
  f16* cth = (f16*)SLOT(0);
  f16* ctl = (f16*)SLOT(1);
  f16* sth = (f16*)SLOT(2);
  f16* stl = (f16*)SLOT(3);
  f16* wbase = (f16*)SLOT(4);
  f16* qw   = wbase;
  f16* kw   = wbase + 1 * 1048576;
  f16* q2wh = wbase + 2 * 1048576;
  f16* q2wl = wbase + 3 * 1048576;
  f16* k2wh = wbase + 4 * 1048576;
  f16* k2wl = wbase + 5 * 1048576;
  f16* vw   = wbase + 6 * 1048576;
  f16* v2w  = vw + 262144;
  f16* f1w  = vw + 524288;
  f16* f2w  = vw + 786432;
  f16*   q2h   = (f16*)SLOT(5);
  f16*   q2l   = (f16*)SLOT(6);
  f16*   k2h   = (f16*)SLOT(7);
  f16*   k2l   = (f16*)SLOT(0);      // after content convs
  f16*   qbuf  = (f16*)SLOT(1);      // after q2 conv
  float* pa1p  = (float*)SLOT(3);    // after k2 conv (4 MB)
  f16*   kbuf  = (f16*)SLOT(6);      // after pa1
  f16*   vbuf  = (f16*)SLOT(3);      // after pa1r
  f16*   v2buf = (f16*)SLOT(0);      // after pa1
  f16*   da_t  = (f16*)SLOT(3);      // after da1
  f16*   pa_t  = (f16*)SLOT(6);      // after da1
  float* stats = (float*)(ws + 134217728);
  float* biasp = (float*)(ws + 134217728 + 32768);
  float* kagg  = (float*)(ws + 134217728 + 32768);
  float* vagg  = (float*)(ws + 134217728 + 557056);
  int*   idxb  = (int*)(ws + 134217728 + 1081344);

  dim3 gconv(32, 4, 4);

  k_mvn_stats<<<4096, 256, 0, stream>>>(content, style, stats);

  k_prep_w_all<<<320, 256, 0, stream>>>(
      q_w, q_b, k_w, k_b, q2_w, q2_b, k2_w, k2_b,
      v_w, v_b, v2_w, v2_b, f1_w, f2_w, stats,
      qw, kw, q2wh, q2wl, k2wh, k2wl, vw, v2w, f1w, f2w, biasp);

  k_prep_x<<<dim3(32,4,2), 256, 0, stream>>>(content, style, cth, ctl, sth, stl);

  // content convs
  k_convT3<<<gconv, 256, 0, stream>>>(cth, ctl, q2wh, q2wl, biasp + 4 * 2048, q2h, q2l);
  k_convT <<<gconv, 256, 0, stream>>>(cth, qw, biasp + 0 * 2048, 1, qbuf);
  // style split conv, then PA1 (frees q2l/k2l)
  k_convT3<<<gconv, 256, 0, stream>>>(sth, stl, k2wh, k2wl, biasp + 5 * 2048, k2h, k2l);
  k_pa1<<<256, 256, 0, stream>>>(q2h, q2l, k2h, k2l, pa1p);
  k_pa1r<<<32, 64, 0, stream>>>(pa1p, idxb);
  // fused k/v/v2 style convs (shares X panels in L2; 3 launches -> 1)
  k_conv3out<<<dim3(32,12,4), 256, 0, stream>>>(sth, kw, vw, v2w, biasp,
                                                kbuf, vbuf, v2buf);

  k_da1<<<2048, 256, 0, stream>>>(kbuf, vbuf, sim_alpha, sim_beta, kagg, vagg);
  k_da2<<<512, 256, 0, stream>>>(qbuf, kagg, vagg, da_t);
  k_pa2<<<2048, 256, 0, stream>>>(q2h, k2h, v2buf, idxb, pa_t);

  k_finalT<<<gconv, 256, 0, stream>>>(da_t, pa_t, f1w, f2w, f1_b, f2_b,
                                      content, (float*)d_out);
}

// Round 9
// 306.890 us; speedup vs baseline: 1.8129x; 1.0245x over previous
//
#include <hip/hip_runtime.h>

typedef unsigned short u16;
typedef unsigned int   u32;
typedef _Float16       f16;

typedef f16   f16x8 __attribute__((ext_vector_type(8)));
typedef f16   f16x4 __attribute__((ext_vector_type(4)));
typedef float f32x4 __attribute__((ext_vector_type(4)));

__device__ __forceinline__ f32x4 mfma16(f16x8 a, f16x8 b, f32x4 c){
  return __builtin_amdgcn_mfma_f32_16x16x32_f16(a, b, c, 0, 0, 0);
}

// async global->LDS, 16B per lane; LDS dest = wave-uniform base + lane*16 (linear)
__device__ __forceinline__ void glds16(const f16* g, f16* l){
  __builtin_amdgcn_global_load_lds(
      (const __attribute__((address_space(1))) void*)g,
      (__attribute__((address_space(3))) void*)l, 16, 0, 0);
}

// ============ 1. per-(b,c) spatial mean / rstd for content & style ============
__global__ __launch_bounds__(256) void k_mvn_stats(
    const float* __restrict__ content, const float* __restrict__ style,
    float* __restrict__ stats)
{
  const int src = blockIdx.x >> 11;
  const int row = blockIdx.x & 2047;
  const float* xp = (src ? style : content) + (size_t)row * 4096;
  const int t = threadIdx.x;
  double s = 0.0, ss = 0.0;
  for(int i = t * 4; i < 4096; i += 1024){
    float4 v = *(const float4*)(xp + i);
    s  += (double)v.x + (double)v.y + (double)v.z + (double)v.w;
    ss += (double)v.x * v.x + (double)v.y * v.y + (double)v.z * v.z + (double)v.w * v.w;
  }
  #pragma unroll
  for(int off = 32; off > 0; off >>= 1){
    s  += __shfl_xor(s, off);
    ss += __shfl_xor(ss, off);
  }
  __shared__ double sh[8];
  const int wid = t >> 6;
  if((t & 63) == 0){ sh[wid] = s; sh[4 + wid] = ss; }
  __syncthreads();
  if(t == 0){
    double S  = sh[0] + sh[1] + sh[2] + sh[3];
    double SS = sh[4] + sh[5] + sh[6] + sh[7];
    float mean = (float)(S * (1.0 / 4096.0));
    float var  = (float)((SS - S * S * (1.0 / 4096.0)) * (1.0 / 4095.0));
    stats[src * 4096 + row] = mean;
    stats[src * 4096 + 2048 + row] = rsqrtf(var + 1e-5f);
  }
}

// ============ 2. ALL weight preps in ONE launch: 10240 flat rows, 8 lanes/row ============
__global__ __launch_bounds__(256) void k_prep_w_all(
    const float* __restrict__ qW,  const float* __restrict__ qB,
    const float* __restrict__ kW,  const float* __restrict__ kB,
    const float* __restrict__ q2W, const float* __restrict__ q2B,
    const float* __restrict__ k2W, const float* __restrict__ k2B,
    const float* __restrict__ vW,  const float* __restrict__ vB,
    const float* __restrict__ v2W, const float* __restrict__ v2B,
    const float* __restrict__ f1W, const float* __restrict__ f2W,
    const float* __restrict__ stats,
    f16* __restrict__ qw, f16* __restrict__ kw,
    f16* __restrict__ q2wh, f16* __restrict__ q2wl,
    f16* __restrict__ k2wh, f16* __restrict__ k2wl,
    f16* __restrict__ vw, f16* __restrict__ v2w,
    f16* __restrict__ f1w, f16* __restrict__ f2w,
    float* __restrict__ biasp)
{
  const int t = threadIdx.x;
  int rid = blockIdx.x * 32 + (t >> 3);
  const float *W; const float *B = nullptr;
  int side = -1, b = 0, o;
  f16 *oh; f16 *ol = nullptr; float* bs = nullptr;
  if(rid < 2048){
    b = rid >> 9; o = rid & 511;
    W = qW; B = qB; side = 0;
    oh = qw + (size_t)(b * 512 + o) * 512;
    bs = biasp + 0 * 2048 + b * 512 + o;
  } else if(rid < 4096){
    rid -= 2048; b = rid >> 9; o = rid & 511;
    W = kW; B = kB; side = 1;
    oh = kw + (size_t)(b * 512 + o) * 512;
    bs = biasp + 1 * 2048 + b * 512 + o;
  } else if(rid < 6144){
    rid -= 4096; b = rid >> 9; o = rid & 511;
    W = q2W; B = q2B; side = 0;
    oh = q2wh + (size_t)(b * 512 + o) * 512;
    ol = q2wl + (size_t)(b * 512 + o) * 512;
    bs = biasp + 4 * 2048 + b * 512 + o;
  } else if(rid < 8192){
    rid -= 6144; b = rid >> 9; o = rid & 511;
    W = k2W; B = k2B; side = 1;
    oh = k2wh + (size_t)(b * 512 + o) * 512;
    ol = k2wl + (size_t)(b * 512 + o) * 512;
    bs = biasp + 5 * 2048 + b * 512 + o;
  } else if(rid < 8704){
    o = rid - 8192; W = vW; B = vB;
    oh = vw + (size_t)o * 512;
    bs = biasp + 2 * 2048 + o;
  } else if(rid < 9216){
    o = rid - 8704; W = v2W; B = v2B;
    oh = v2w + (size_t)o * 512;
    bs = biasp + 3 * 2048 + o;
  } else if(rid < 9728){
    o = rid - 9216; W = f1W;
    oh = f1w + (size_t)o * 512;
  } else {
    o = rid - 9728; W = f2W;
    oh = f2w + (size_t)o * 512;
  }
  const float* mp = (side >= 0) ? stats + side * 4096 + b * 512 : nullptr;
  const float* rp = (side >= 0) ? mp + 2048 : nullptr;
  const int c0 = (t & 7) * 64;
  float dot = 0.f;
  #pragma unroll
  for(int i = 0; i < 64; i += 8){
    int c = c0 + i;
    float w[8];
    *(float4*)(w)     = *(const float4*)(W + (size_t)o * 512 + c);
    *(float4*)(w + 4) = *(const float4*)(W + (size_t)o * 512 + c + 4);
    f16x8 h8, l8;
    #pragma unroll
    for(int j = 0; j < 8; j++){
      float wp = w[j];
      if(side >= 0){
        float r = rp[c + j];
        dot += wp * mp[c + j] * r;
        wp *= r;
      }
      f16 h = (f16)wp;
      h8[j] = h; l8[j] = (f16)(wp - (float)h);
    }
    *(f16x8*)(oh + c) = h8;
    if(ol) *(f16x8*)(ol + c) = l8;
  }
  if(bs){
    dot += __shfl_xor(dot, 1); dot += __shfl_xor(dot, 2); dot += __shfl_xor(dot, 4);
    if((t & 7) == 0) *bs = B[o] - dot;
  }
}

// ============ 3. X prep: transpose [c][s] f32 -> Xt [s][c] f16 hi+lo ============
__global__ __launch_bounds__(256) void k_prep_x(
    const float* __restrict__ content, const float* __restrict__ style,
    f16* __restrict__ cth, f16* __restrict__ ctl,
    f16* __restrict__ sth, f16* __restrict__ stl)
{
  const int side = blockIdx.z;
  const int b = blockIdx.y;
  const int s0 = blockIdx.x * 128;
  const float* Xb = (side ? style : content) + (size_t)b * 512 * 4096;
  f16* Oh = (side ? sth : cth) + (size_t)b * 4096 * 512;
  f16* Ol = (side ? stl : ctl) + (size_t)b * 4096 * 512;
  __shared__ float Xs[32][132];
  const int t = threadIdx.x;
  const int s = t >> 1, half = t & 1;
  for(int cc = 0; cc < 512; cc += 32){
    __syncthreads();
    #pragma unroll
    for(int u = 0; u < 4; u++){
      int q = t + u * 256;
      int row = q >> 5, f4 = q & 31;
      float4 v = *(const float4*)(Xb + (size_t)(cc + row) * 4096 + s0 + f4 * 4);
      *(float4*)(&Xs[row][f4 * 4]) = v;
    }
    __syncthreads();
    f16x8 h0, h1, l0, l1;
    #pragma unroll
    for(int i = 0; i < 8; i++){
      float x = Xs[half * 16 + i][s];
      f16 h = (f16)x; h0[i] = h; l0[i] = (f16)(x - (float)h);
    }
    #pragma unroll
    for(int i = 0; i < 8; i++){
      float x = Xs[half * 16 + 8 + i][s];
      f16 h = (f16)x; h1[i] = h; l1[i] = (f16)(x - (float)h);
    }
    size_t o = (size_t)(s0 + s) * 512 + cc + half * 16;
    *(f16x8*)(Oh + o) = h0; *(f16x8*)(Oh + o + 8) = h1;
    *(f16x8*)(Ol + o) = l0; *(f16x8*)(Ol + o + 8) = l1;
  }
}

// ============ 4. conv1x1 GEMM single-pass, global_load_lds + XOR-swizzled reads ============
__global__ __launch_bounds__(256) void k_convT(
    const f16* __restrict__ Xt, const f16* __restrict__ Wp,
    const float* __restrict__ bias, int bw, f16* __restrict__ Out)
{
  const int b = blockIdx.z;
  const int o0 = blockIdx.y * 128;
  const int s0 = blockIdx.x * 128;
  const f16* Xb = Xt + (size_t)b * 4096 * 512;
  const f16* Wb = Wp + (bw ? (size_t)b * 262144 : 0);
  const float* bp = bias + (bw ? b * 512 : 0);
  f16* Ob = Out + (size_t)b * 512 * 4096;
  __shared__ f16 As[4096];   // [128][32] linear (glds dest)
  __shared__ f16 Bs[4096];
  const int t = threadIdx.x;
  const int lane = t & 63, wid = t >> 6;
  const int wm = (wid >> 1) * 64, wn = (wid & 1) * 64;
  const int lr = lane & 15, lg = lane >> 4;
  const int sr = lane >> 2, sc = lane & 3;   // staging sub-row / chunk
  f32x4 acc[4][4] = {};
  for(int kk = 0; kk < 512; kk += 32){
    __syncthreads();
    #pragma unroll
    for(int i = 0; i < 2; i++){
      int r0 = wid * 32 + i * 16;
      int r = r0 + sr;
      int cs = (sc ^ ((r >> 1) & 3)) << 3;   // inverse-swizzled global chunk
      glds16(Wb + (size_t)(o0 + r) * 512 + kk + cs, As + r0 * 32);
      glds16(Xb + (size_t)(s0 + r) * 512 + kk + cs, Bs + r0 * 32);
    }
    __syncthreads();
    f16x8 av[4], bv[4];
    #pragma unroll
    for(int mi = 0; mi < 4; mi++){
      int row = wm + mi * 16 + lr;
      av[mi] = *(const f16x8*)(As + row * 32 + ((lg ^ ((row >> 1) & 3)) << 3));
    }
    #pragma unroll
    for(int ni = 0; ni < 4; ni++){
      int row = wn + ni * 16 + lr;
      bv[ni] = *(const f16x8*)(Bs + row * 32 + ((lg ^ ((row >> 1) & 3)) << 3));
    }
    #pragma unroll
    for(int mi = 0; mi < 4; mi++){
      #pragma unroll
      for(int ni = 0; ni < 4; ni++)
        acc[mi][ni] = mfma16(av[mi], bv[ni], acc[mi][ni]);
    }
  }
  #pragma unroll
  for(int mi = 0; mi < 4; mi++){
    #pragma unroll
    for(int ni = 0; ni < 4; ni++){
      #pragma unroll
      for(int j = 0; j < 4; j++){
        int o = o0 + wm + mi * 16 + lg * 4 + j;
        int s = s0 + wn + ni * 16 + lr;
        Ob[(size_t)o * 4096 + s] = (f16)(acc[mi][ni][j] + bp[o]);
      }
    }
  }
}

// ============ 4b. fused 3-output style conv: k (batched W), v, v2 ============
__global__ __launch_bounds__(256) void k_conv3out(
    const f16* __restrict__ Xt,
    const f16* __restrict__ Wk, const f16* __restrict__ Wv, const f16* __restrict__ Wv2,
    const float* __restrict__ biasp,
    f16* __restrict__ Ok, f16* __restrict__ Ov, f16* __restrict__ Ov2)
{
  const int b = blockIdx.z;
  const int seg = blockIdx.y >> 2;             // 0=k 1=v 2=v2
  const int o0 = (blockIdx.y & 3) * 128;
  const int s0 = blockIdx.x * 128;
  const f16* Xb = Xt + (size_t)b * 4096 * 512;
  const f16* Wb = seg == 0 ? Wk + (size_t)b * 262144 : (seg == 1 ? Wv : Wv2);
  const float* bp = biasp + (seg == 0 ? 1 * 2048 + b * 512 : (seg == 1 ? 2 * 2048 : 3 * 2048));
  f16* Ob = (seg == 0 ? Ok : (seg == 1 ? Ov : Ov2)) + (size_t)b * 512 * 4096;
  __shared__ f16 As[4096];
  __shared__ f16 Bs[4096];
  const int t = threadIdx.x;
  const int lane = t & 63, wid = t >> 6;
  const int wm = (wid >> 1) * 64, wn = (wid & 1) * 64;
  const int lr = lane & 15, lg = lane >> 4;
  const int sr = lane >> 2, sc = lane & 3;
  f32x4 acc[4][4] = {};
  for(int kk = 0; kk < 512; kk += 32){
    __syncthreads();
    #pragma unroll
    for(int i = 0; i < 2; i++){
      int r0 = wid * 32 + i * 16;
      int r = r0 + sr;
      int cs = (sc ^ ((r >> 1) & 3)) << 3;
      glds16(Wb + (size_t)(o0 + r) * 512 + kk + cs, As + r0 * 32);
      glds16(Xb + (size_t)(s0 + r) * 512 + kk + cs, Bs + r0 * 32);
    }
    __syncthreads();
    f16x8 av[4], bv[4];
    #pragma unroll
    for(int mi = 0; mi < 4; mi++){
      int row = wm + mi * 16 + lr;
      av[mi] = *(const f16x8*)(As + row * 32 + ((lg ^ ((row >> 1) & 3)) << 3));
    }
    #pragma unroll
    for(int ni = 0; ni < 4; ni++){
      int row = wn + ni * 16 + lr;
      bv[ni] = *(const f16x8*)(Bs + row * 32 + ((lg ^ ((row >> 1) & 3)) << 3));
    }
    #pragma unroll
    for(int mi = 0; mi < 4; mi++){
      #pragma unroll
      for(int ni = 0; ni < 4; ni++)
        acc[mi][ni] = mfma16(av[mi], bv[ni], acc[mi][ni]);
    }
  }
  #pragma unroll
  for(int mi = 0; mi < 4; mi++){
    #pragma unroll
    for(int ni = 0; ni < 4; ni++){
      #pragma unroll
      for(int j = 0; j < 4; j++){
        int o = o0 + wm + mi * 16 + lg * 4 + j;
        int s = s0 + wn + ni * 16 + lr;
        Ob[(size_t)o * 4096 + s] = (f16)(acc[mi][ni][j] + bp[o]);
      }
    }
  }
}

// ============ 5. conv1x1 GEMM split-3 (hi/lo), glds staging ============
__global__ __launch_bounds__(256) void k_convT3(
    const f16* __restrict__ Xh, const f16* __restrict__ Xl,
    const f16* __restrict__ Wh, const f16* __restrict__ Wl,
    const float* __restrict__ bias, f16* __restrict__ Oh, f16* __restrict__ Ol)
{
  const int b = blockIdx.z;
  const int o0 = blockIdx.y * 128;
  const int s0 = blockIdx.x * 128;
  const f16* Xhb = Xh + (size_t)b * 4096 * 512;
  const f16* Xlb = Xl + (size_t)b * 4096 * 512;
  const f16* Whb = Wh + (size_t)b * 262144;
  const f16* Wlb = Wl + (size_t)b * 262144;
  const float* bp = bias + b * 512;
  f16* Ohb = Oh + (size_t)b * 512 * 4096;
  f16* Olb = Ol + (size_t)b * 512 * 4096;
  __shared__ f16 Ah[4096], Al[4096], Bh[4096], Bl[4096];
  const int t = threadIdx.x;
  const int lane = t & 63, wid = t >> 6;
  const int wm = (wid >> 1) * 64, wn = (wid & 1) * 64;
  const int lr = lane & 15, lg = lane >> 4;
  const int sr = lane >> 2, sc = lane & 3;
  f32x4 acc[4][4] = {};
  for(int kk = 0; kk < 512; kk += 32){
    __syncthreads();
    #pragma unroll
    for(int i = 0; i < 2; i++){
      int r0 = wid * 32 + i * 16;
      int r = r0 + sr;
      int cs = (sc ^ ((r >> 1) & 3)) << 3;
      size_t wsrc = (size_t)(o0 + r) * 512 + kk + cs;
      size_t xsrc = (size_t)(s0 + r) * 512 + kk + cs;
      glds16(Whb + wsrc, Ah + r0 * 32);
      glds16(Wlb + wsrc, Al + r0 * 32);
      glds16(Xhb + xsrc, Bh + r0 * 32);
      glds16(Xlb + xsrc, Bl + r0 * 32);
    }
    __syncthreads();
    f16x8 ah[4], alo[4], bh[4], blo[4];
    #pragma unroll
    for(int mi = 0; mi < 4; mi++){
      int row = wm + mi * 16 + lr;
      int off = row * 32 + ((lg ^ ((row >> 1) & 3)) << 3);
      ah[mi]  = *(const f16x8*)(Ah + off);
      alo[mi] = *(const f16x8*)(Al + off);
    }
    #pragma unroll
    for(int ni = 0; ni < 4; ni++){
      int row = wn + ni * 16 + lr;
      int off = row * 32 + ((lg ^ ((row >> 1) & 3)) << 3);
      bh[ni]  = *(const f16x8*)(Bh + off);
      blo[ni] = *(const f16x8*)(Bl + off);
    }
    #pragma unroll
    for(int mi = 0; mi < 4; mi++){
      #pragma unroll
      for(int ni = 0; ni < 4; ni++){
        f32x4 a = acc[mi][ni];
        a = mfma16(ah[mi],  bh[ni],  a);
        a = mfma16(ah[mi],  blo[ni], a);
        a = mfma16(alo[mi], bh[ni],  a);
        acc[mi][ni] = a;
      }
    }
  }
  #pragma unroll
  for(int mi = 0; mi < 4; mi++){
    #pragma unroll
    for(int ni = 0; ni < 4; ni++){
      #pragma unroll
      for(int j = 0; j < 4; j++){
        int o = o0 + wm + mi * 16 + lg * 4 + j;
        int s = s0 + wn + ni * 16 + lr;
        float v = acc[mi][ni][j] + bp[o];
        f16 h = (f16)v;
        Ohb[(size_t)o * 4096 + s] = h;
        Olb[(size_t)o * 4096 + s] = (f16)(v - (float)h);
      }
    }
  }
}

// ============ 6. DA aggregation — XCD-grouped so line-sharing siblings colocate ============
__global__ __launch_bounds__(256) void k_da1(
    const f16* __restrict__ K, const f16* __restrict__ V,
    const float* __restrict__ alpha_p, const float* __restrict__ beta_p,
    float* __restrict__ kagg, float* __restrict__ vagg)
{
  const int hw = blockIdx.x;
  const int xcd = hw & 7, i = hw >> 3;
  const int g = xcd * 32 + (i >> 3);
  const int bh = g >> 3;
  const int x  = (g & 7) * 8 + (i & 7);
  const f16* Kb = K + (size_t)bh * 64 * 4096;
  const f16* Vb = V + (size_t)bh * 64 * 4096;
  __shared__ float kl[64][65];
  __shared__ float vl[64][65];
  __shared__ float kc[64], vc[64], simv[64];
  const int t = threadIdx.x;
  const int c = t >> 2, yp = t & 3;
  const int xb = (x >> 3) * 512 + (x & 7) * 8;
  #pragma unroll
  for(int u = 0; u < 2; u++){
    int yh = yp * 2 + u;
    f16x8 k8 = *(const f16x8*)(Kb + (size_t)c * 4096 + xb + yh * 64);
    f16x8 v8 = *(const f16x8*)(Vb + (size_t)c * 4096 + xb + yh * 64);
    #pragma unroll
    for(int j = 0; j < 8; j++){
      kl[c][yh * 8 + j] = (float)k8[j];
      vl[c][yh * 8 + j] = (float)v8[j];
    }
  }
  __syncthreads();
  float sk = 0.f, sv = 0.f;
  for(int yy = yp * 16; yy < yp * 16 + 16; yy++){ sk += kl[c][yy]; sv += vl[c][yy]; }
  sk += __shfl_xor(sk, 1); sk += __shfl_xor(sk, 2);
  sv += __shfl_xor(sv, 1); sv += __shfl_xor(sv, 2);
  if(yp == 0){ kc[c] = sk * (1.f / 64.f); vc[c] = sv * (1.f / 64.f); }
  __syncthreads();
  const int y = t >> 2, cp = t & 3;
  float d = 0.f;
  for(int cc = cp * 16; cc < cp * 16 + 16; cc++) d += kc[cc] * kl[cc][y];
  d += __shfl_xor(d, 1); d += __shfl_xor(d, 2);
  if(cp == 0) simv[y] = 1.f / (1.f + expf(-(beta_p[0] + alpha_p[0] * d)));
  __syncthreads();
  float ak = 0.f, av = 0.f;
  for(int yy = yp * 16; yy < yp * 16 + 16; yy++){
    float sm = simv[yy];
    ak += sm * kl[c][yy]; av += sm * vl[c][yy];
  }
  ak += __shfl_xor(ak, 1); ak += __shfl_xor(ak, 2);
  av += __shfl_xor(av, 1); av += __shfl_xor(av, 2);
  if(yp == 0){
    size_t o = ((size_t)bh * 64 + x) * 64 + c;
    kagg[o] = (ak + kc[c]) * (1.f / 65.f);
    vagg[o] = (av + vc[c]) * (1.f / 65.f);
  }
}

// ============ 7. DA attention MFMA; output TRANSPOSED [s][c] for final ============
__global__ __launch_bounds__(256) void k_da2(
    const f16* __restrict__ Q, const float* __restrict__ kagg,
    const float* __restrict__ vagg, f16* __restrict__ OutT)
{
  const int bh = blockIdx.x >> 4;
  const int s0 = (blockIdx.x & 15) << 8;
  const int b_ = bh >> 3, hd = bh & 7;
  const f16* Qb = Q + (size_t)bh * 64 * 4096;
  f16* Ot = OutT + (size_t)b_ * 4096 * 512 + hd * 64;

  __shared__ __align__(16) f16 Qt[256][72];
  __shared__ __align__(16) f16 Kt[64][72];
  __shared__ __align__(16) f16 Vt[64][72];
  const int t = threadIdx.x;
  const int lane = t & 63, w = t >> 6;
  const int lr = lane & 15, lg = lane >> 4;

  {
    const int so = t & 31;
    #pragma unroll
    for(int pass = 0; pass < 8; pass++){
      int c = (t >> 5) + pass * 8;
      f16x8 q8 = *(const f16x8*)(Qb + (size_t)c * 4096 + s0 + so * 8);
      #pragma unroll
      for(int j = 0; j < 8; j++){
        int s = so * 8 + j;
        int col = (((c >> 3) ^ (s & 7)) << 3) | (c & 7);
        Qt[s][col] = q8[j];
      }
    }
  }
  {
    const int z = t >> 2, c0 = (t & 3) * 16;
    #pragma unroll
    for(int u = 0; u < 4; u++){
      float4 v = *(const float4*)(kagg + (size_t)bh * 4096 + z * 64 + c0 + u * 4);
      float vv[4] = {v.x, v.y, v.z, v.w};
      #pragma unroll
      for(int j = 0; j < 4; j++){
        int c = c0 + u * 4 + j;
        int col = (((c >> 3) ^ (z & 7)) << 3) | (c & 7);
        Kt[z][col] = (f16)vv[j];
      }
    }
    #pragma unroll
    for(int u = 0; u < 4; u++){
      float4 v = *(const float4*)(vagg + (size_t)bh * 4096 + z * 64 + c0 + u * 4);
      float vv[4] = {v.x, v.y, v.z, v.w};
      #pragma unroll
      for(int j = 0; j < 4; j++){
        int c = c0 + u * 4 + j;
        int col = (((z >> 3) ^ (c & 7)) << 3) | (z & 7);
        Vt[c][col] = (f16)vv[j];
      }
    }
  }
  __syncthreads();

  f32x4 acc[4][4] = {};
  #pragma unroll
  for(int kc = 0; kc < 2; kc++){
    f16x8 af[4], bf[4];
    #pragma unroll
    for(int mi = 0; mi < 4; mi++){
      int row = w * 64 + mi * 16 + lr;
      af[mi] = *(const f16x8*)(&Qt[row][(((kc * 4 + lg) ^ (row & 7)) << 3)]);
    }
    #pragma unroll
    for(int ni = 0; ni < 4; ni++){
      int row = ni * 16 + lr;
      bf[ni] = *(const f16x8*)(&Kt[row][(((kc * 4 + lg) ^ (row & 7)) << 3)]);
    }
    #pragma unroll
    for(int mi = 0; mi < 4; mi++){
      #pragma unroll
      for(int ni = 0; ni < 4; ni++)
        acc[mi][ni] = mfma16(af[mi], bf[ni], acc[mi][ni]);
    }
  }

  #pragma unroll
  for(int mi = 0; mi < 4; mi++){
    #pragma unroll
    for(int j = 0; j < 4; j++){
      float v0 = acc[mi][0][j], v1 = acc[mi][1][j], v2 = acc[mi][2][j], v3 = acc[mi][3][j];
      float m = fmaxf(fmaxf(v0, v1), fmaxf(v2, v3));
      m = fmaxf(m, __shfl_xor(m, 1)); m = fmaxf(m, __shfl_xor(m, 2));
      m = fmaxf(m, __shfl_xor(m, 4)); m = fmaxf(m, __shfl_xor(m, 8));
      float e0 = expf(v0 - m), e1 = expf(v1 - m), e2 = expf(v2 - m), e3 = expf(v3 - m);
      float sm = e0 + e1 + e2 + e3;
      sm += __shfl_xor(sm, 1); sm += __shfl_xor(sm, 2);
      sm += __shfl_xor(sm, 4); sm += __shfl_xor(sm, 8);
      float inv = 1.f / sm;
      float ev[4] = {e0, e1, e2, e3};
      int row = w * 64 + mi * 16 + lg * 4 + j;
      #pragma unroll
      for(int ni = 0; ni < 4; ni++){
        int z = lr + 16 * ni;
        int col = (((z >> 3) ^ (row & 7)) << 3) | (z & 7);
        Qt[row][col] = (f16)(ev[ni] * inv);
      }
    }
  }
  // no barrier: each wave touches only its own Qt rows; Kt/Vt read-only

  f32x4 acc2[4][4] = {};
  #pragma unroll
  for(int kc = 0; kc < 2; kc++){
    f16x8 af[4], bf[4];
    #pragma unroll
    for(int mi = 0; mi < 4; mi++){
      int row = w * 64 + mi * 16 + lr;
      af[mi] = *(const f16x8*)(&Qt[row][(((kc * 4 + lg) ^ (row & 7)) << 3)]);
    }
    #pragma unroll
    for(int ni = 0; ni < 4; ni++){
      int row = ni * 16 + lr;
      bf[ni] = *(const f16x8*)(&Vt[row][(((kc * 4 + lg) ^ (row & 7)) << 3)]);
    }
    #pragma unroll
    for(int mi = 0; mi < 4; mi++){
      #pragma unroll
      for(int ni = 0; ni < 4; ni++)
        acc2[mi][ni] = mfma16(af[mi], bf[ni], acc2[mi][ni]);
    }
  }

  #pragma unroll
  for(int mi = 0; mi < 4; mi++){
    #pragma unroll
    for(int j = 0; j < 4; j++){
      size_t srow = (size_t)(s0 + w * 64 + mi * 16 + lg * 4 + j) * 512;
      #pragma unroll
      for(int ni = 0; ni < 4; ni++)
        Ot[srow + ni * 16 + lr] = (f16)acc2[mi][ni][j];
    }
  }
}

// ============ 8. PA1 split-K MFMA ============
__global__ __launch_bounds__(256) void k_pa1(
    const f16* __restrict__ Qh, const f16* __restrict__ Ql,
    const f16* __restrict__ Kh, const f16* __restrict__ Kl,
    float* __restrict__ pa1p)
{
  const int slice = blockIdx.x & 7;
  const int bh = blockIdx.x >> 3;
  const size_t base = (size_t)bh * 64 * 4096;
  __shared__ f16 Ah[2][64][72], Al[2][64][72], Bh[2][64][72], Bl[2][64][72];
  const int t = threadIdx.x;
  const int lane = t & 63, wid = t >> 6;
  const int wm = (wid >> 1) * 32, wn = (wid & 1) * 32;
  const int lr = lane & 15, lg = lane >> 4;
  f32x4 acc[2][2] = {};
  for(int chunk = 0; chunk < 4; chunk++){
    const int c0 = slice * 8 + chunk * 2;
    __syncthreads();
    #pragma unroll
    for(int cc = 0; cc < 2; cc++){
      size_t cbase = base + (size_t)(c0 + cc) * 4096;
      #pragma unroll
      for(int u = 0; u < 2; u++){
        int e = u * 256 + t;
        int x = e >> 3, yh = e & 7;
        size_t src = cbase + (size_t)((x >> 3) * 512 + (x & 7) * 8 + yh * 64);
        int dst = yh * 8;
        *(f16x8*)(&Ah[cc][x][dst]) = *(const f16x8*)(Qh + src);
        *(f16x8*)(&Al[cc][x][dst]) = *(const f16x8*)(Ql + src);
        *(f16x8*)(&Bh[cc][x][dst]) = *(const f16x8*)(Kh + src);
        *(f16x8*)(&Bl[cc][x][dst]) = *(const f16x8*)(Kl + src);
      }
    }
    __syncthreads();
    #pragma unroll
    for(int cc = 0; cc < 2; cc++){
      #pragma unroll
      for(int kc = 0; kc < 2; kc++){
        f16x8 ah[2], alo[2], bh[2], blo[2];
        #pragma unroll
        for(int mi = 0; mi < 2; mi++){
          ah[mi]  = *(const f16x8*)(&Ah[cc][wm + mi * 16 + lr][kc * 32 + lg * 8]);
          alo[mi] = *(const f16x8*)(&Al[cc][wm + mi * 16 + lr][kc * 32 + lg * 8]);
        }
        #pragma unroll
        for(int ni = 0; ni < 2; ni++){
          bh[ni]  = *(const f16x8*)(&Bh[cc][wn + ni * 16 + lr][kc * 32 + lg * 8]);
          blo[ni] = *(const f16x8*)(&Bl[cc][wn + ni * 16 + lr][kc * 32 + lg * 8]);
        }
        #pragma unroll
        for(int mi = 0; mi < 2; mi++){
          #pragma unroll
          for(int ni = 0; ni < 2; ni++){
            f32x4 a = acc[mi][ni];
            a = mfma16(ah[mi],  bh[ni],  a);
            a = mfma16(ah[mi],  blo[ni], a);
            a = mfma16(alo[mi], bh[ni],  a);
            acc[mi][ni] = a;
          }
        }
      }
    }
  }
  float* outp = pa1p + ((size_t)bh * 8 + slice) * 4096;
  #pragma unroll
  for(int mi = 0; mi < 2; mi++){
    #pragma unroll
    for(int ni = 0; ni < 2; ni++){
      #pragma unroll
      for(int j = 0; j < 4; j++){
        int x = wm + mi * 16 + lg * 4 + j;
        int z = wn + ni * 16 + lr;
        outp[x * 64 + z] = acc[mi][ni][j];
      }
    }
  }
}

// ============ 8b. reduce partials + argmax ============
__global__ __launch_bounds__(64) void k_pa1r(
    const float* __restrict__ pa1p, int* __restrict__ idx)
{
  const int bh = blockIdx.x;
  const int x = threadIdx.x;
  const float* p = pa1p + (size_t)bh * 8 * 4096 + x * 64;
  float best = -1e30f; int bi = 0;
  for(int z = 0; z < 64; z += 4){
    float4 v = *(const float4*)(p + z);
    #pragma unroll
    for(int sl = 1; sl < 8; sl++){
      float4 w = *(const float4*)(p + sl * 4096 + z);
      v.x += w.x; v.y += w.y; v.z += w.z; v.w += w.w;
    }
    if(v.x > best){ best = v.x; bi = z; }
    if(v.y > best){ best = v.y; bi = z + 1; }
    if(v.z > best){ best = v.z; bi = z + 2; }
    if(v.w > best){ best = v.w; bi = z + 3; }
  }
  idx[bh * 64 + x] = bi;
}

// ============ 9. PA intra-block attention; output TRANSPOSED [s][c] ============
__global__ __launch_bounds__(256) void k_pa2(
    const f16* __restrict__ Qh, const f16* __restrict__ Kh,
    const f16* __restrict__ V2, const int* __restrict__ idx, f16* __restrict__ OutT)
{
  const int hw = blockIdx.x;
  const int bh = (hw & 7) * 4 + ((hw >> 3) >> 6);
  const int x  = (hw >> 3) & 63;
  const int b_ = bh >> 3, hd = bh & 7;
  const size_t base = (size_t)bh * 64 * 4096;
  f16* Ot = OutT + (size_t)b_ * 4096 * 512 + hd * 64;

  __shared__ __align__(16) char Ubuf[18432];
  __shared__ f16 Vn[64][72];
  __shared__ f16 Ps[64][72];
  f16   (*Qt)[72] = (f16(*)[72])Ubuf;
  f16   (*Kt)[72] = (f16(*)[72])(Ubuf + 9216);
  float (*Lf)[66] = (float(*)[66])Ubuf;
  float (*Os)[67] = (float(*)[67])Ubuf;

  const int t = threadIdx.x;
  const int lane = t & 63, wid = t >> 6;
  const int wm = (wid >> 1) * 32, wn = (wid & 1) * 32;
  const int lr = lane & 15, lg = lane >> 4;

  const int xk = idx[bh * 64 + x];
  const int xb = (x >> 3) * 512 + (x & 7) * 8;
  const int kb = (xk >> 3) * 512 + (xk & 7) * 8;

  {
    const int c = t >> 2, q4 = t & 3;
    #pragma unroll
    for(int u = 0; u < 2; u++){
      int yh = q4 * 2 + u;
      f16x8 q8 = *(const f16x8*)(Qh + base + (size_t)c * 4096 + xb + yh * 64);
      f16x8 k8 = *(const f16x8*)(Kh + base + (size_t)c * 4096 + kb + yh * 64);
      f16x8 v8 = *(const f16x8*)(V2 + base + (size_t)c * 4096 + kb + yh * 64);
      int col = ((((c >> 3) ^ yh) & 7) << 3) + (c & 7);
      #pragma unroll
      for(int j = 0; j < 8; j++){
        Qt[yh * 8 + j][col] = q8[j];
        Kt[yh * 8 + j][col] = k8[j];
      }
      *(f16x8*)(&Vn[c][yh * 8]) = v8;
    }
  }
  __syncthreads();

  f32x4 acc[2][2] = {};
  #pragma unroll
  for(int kc = 0; kc < 2; kc++){
    f16x8 af[2], bf[2];
    #pragma unroll
    for(int mi = 0; mi < 2; mi++){
      int row = wm + mi * 16 + lr;
      af[mi] = *(const f16x8*)(&Qt[row][((((kc * 4 + lg) ^ (row >> 3)) & 7) << 3)]);
    }
    #pragma unroll
    for(int ni = 0; ni < 2; ni++){
      int row = wn + ni * 16 + lr;
      bf[ni] = *(const f16x8*)(&Kt[row][((((kc * 4 + lg) ^ (row >> 3)) & 7) << 3)]);
    }
    #pragma unroll
    for(int mi = 0; mi < 2; mi++){
      #pragma unroll
      for(int ni = 0; ni < 2; ni++)
        acc[mi][ni] = mfma16(af[mi], bf[ni], acc[mi][ni]);
    }
  }
  __syncthreads();
  #pragma unroll
  for(int mi = 0; mi < 2; mi++){
    #pragma unroll
    for(int ni = 0; ni < 2; ni++){
      #pragma unroll
      for(int j = 0; j < 4; j++)
        Lf[wm + mi * 16 + lg * 4 + j][wn + ni * 16 + lr] = acc[mi][ni][j];
    }
  }
  __syncthreads();

  {
    const int y = t >> 2, zp = t & 3;
    float l[16];
    #pragma unroll
    for(int i = 0; i < 16; i++) l[i] = Lf[y][zp * 16 + i];
    float m = l[0];
    #pragma unroll
    for(int i = 1; i < 16; i++) m = fmaxf(m, l[i]);
    m = fmaxf(m, __shfl_xor(m, 1)); m = fmaxf(m, __shfl_xor(m, 2));
    float sum = 0.f;
    #pragma unroll
    for(int i = 0; i < 16; i++){ l[i] = expf(l[i] - m); sum += l[i]; }
    sum += __shfl_xor(sum, 1); sum += __shfl_xor(sum, 2);
    float inv = 1.f / sum;
    f16x8 p0, p1;
    #pragma unroll
    for(int i = 0; i < 8; i++){ p0[i] = (f16)(l[i] * inv); p1[i] = (f16)(l[8 + i] * inv); }
    *(f16x8*)(&Ps[y][zp * 16]) = p0;
    *(f16x8*)(&Ps[y][zp * 16 + 8]) = p1;
  }
  __syncthreads();

  f32x4 acc2[2][2] = {};
  #pragma unroll
  for(int kc = 0; kc < 2; kc++){
    f16x8 af[2], bf[2];
    #pragma unroll
    for(int mi = 0; mi < 2; mi++)
      af[mi] = *(const f16x8*)(&Ps[wm + mi * 16 + lr][kc * 32 + lg * 8]);
    #pragma unroll
    for(int ni = 0; ni < 2; ni++)
      bf[ni] = *(const f16x8*)(&Vn[wn + ni * 16 + lr][kc * 32 + lg * 8]);
    #pragma unroll
    for(int mi = 0; mi < 2; mi++){
      #pragma unroll
      for(int ni = 0; ni < 2; ni++)
        acc2[mi][ni] = mfma16(af[mi], bf[ni], acc2[mi][ni]);
    }
  }
  #pragma unroll
  for(int mi = 0; mi < 2; mi++){
    #pragma unroll
    for(int ni = 0; ni < 2; ni++){
      #pragma unroll
      for(int j = 0; j < 4; j++)
        Os[wn + ni * 16 + lr][wm + mi * 16 + lg * 4 + j] = acc2[mi][ni][j];
    }
  }
  __syncthreads();

  {
    const int y = t >> 2, cq = (t & 3) * 16;
    size_t srow = (size_t)(xb + (y >> 3) * 64 + (y & 7)) * 512;
    f16x8 w0, w1;
    #pragma unroll
    for(int i = 0; i < 8; i++){ w0[i] = (f16)Os[cq + i][y]; w1[i] = (f16)Os[cq + 8 + i][y]; }
    *(f16x8*)(Ot + srow + cq) = w0;
    *(f16x8*)(Ot + srow + cq + 8) = w1;
  }
}

// ============ 10. Final: f1'.DA_t + f2'.PA_t + biases + content -> f32 ============
__global__ __launch_bounds__(256) void k_finalT(
    const f16* __restrict__ X1t, const f16* __restrict__ X2t,
    const f16* __restrict__ W1p, const f16* __restrict__ W2p,
    const float* __restrict__ B1, const float* __restrict__ B2,
    const float* __restrict__ content, float* __restrict__ out)
{
  const int b = blockIdx.z;
  const int o0 = blockIdx.y * 128;
  const int s0 = blockIdx.x * 128;
  __shared__ f16 As[4096];
  __shared__ f16 Bs[4096];
  const int t = threadIdx.x;
  const int lane = t & 63, wid = t >> 6;
  const int wm = (wid >> 1) * 64, wn = (wid & 1) * 64;
  const int lr = lane & 15, lg = lane >> 4;
  const int sr = lane >> 2, sc = lane & 3;
  f32x4 acc[4][4] = {};
  for(int pass = 0; pass < 2; pass++){
    const f16* Xb = (pass ? X2t : X1t) + (size_t)b * 4096 * 512;
    const f16* Wb = pass ? W2p : W1p;
    for(int kk = 0; kk < 512; kk += 32){
      __syncthreads();
      #pragma unroll
      for(int i = 0; i < 2; i++){
        int r0 = wid * 32 + i * 16;
        int r = r0 + sr;
        int cs = (sc ^ ((r >> 1) & 3)) << 3;
        glds16(Wb + (size_t)(o0 + r) * 512 + kk + cs, As + r0 * 32);
        glds16(Xb + (size_t)(s0 + r) * 512 + kk + cs, Bs + r0 * 32);
      }
      __syncthreads();
      f16x8 av[4], bv[4];
      #pragma unroll
      for(int mi = 0; mi < 4; mi++){
        int row = wm + mi * 16 + lr;
        av[mi] = *(const f16x8*)(As + row * 32 + ((lg ^ ((row >> 1) & 3)) << 3));
      }
      #pragma unroll
      for(int ni = 0; ni < 4; ni++){
        int row = wn + ni * 16 + lr;
        bv[ni] = *(const f16x8*)(Bs + row * 32 + ((lg ^ ((row >> 1) & 3)) << 3));
      }
      #pragma unroll
      for(int mi = 0; mi < 4; mi++){
        #pragma unroll
        for(int ni = 0; ni < 4; ni++)
          acc[mi][ni] = mfma16(av[mi], bv[ni], acc[mi][ni]);
      }
    }
  }
  #pragma unroll
  for(int mi = 0; mi < 4; mi++){
    #pragma unroll
    for(int ni = 0; ni < 4; ni++){
      #pragma unroll
      for(int j = 0; j < 4; j++){
        int o = o0 + wm + mi * 16 + lg * 4 + j;
        int s = s0 + wn + ni * 16 + lr;
        size_t gi = ((size_t)b * 512 + o) * 4096 + s;
        out[gi] = acc[mi][ni][j] + B1[o] + B2[o] + content[gi];
      }
    }
  }
}

extern "C" void kernel_launch(void* const* d_in, const int* in_sizes, int n_in,
                              void* d_out, int out_size, void* d_ws, size_t ws_size,
                              hipStream_t stream) {
  (void)in_sizes; (void)n_in; (void)out_size; (void)ws_size;
  const float* content = (const float*)d_in[0];
  const float* style   = (const float*)d_in[1];
  const float* q_w  = (const float*)d_in[2];  const float* q_b  = (const float*)d_in[3];
  const float* k_w  = (const float*)d_in[4];  const float* k_b  = (const float*)d_in[5];
  const float* v_w  = (const float*)d_in[6];  const float* v_b  = (const float*)d_in[7];
  const float* q2_w = (const float*)d_in[8];  const float* q2_b = (const float*)d_in[9];
  const float* k2_w = (const float*)d_in[10]; const float* k2_b = (const float*)d_in[11];
  const float* v2_w = (const float*)d_in[12]; const float* v2_b = (const float*)d_in[13];
  const float* f1_w = (const float*)d_in[14]; const float* f1_b = (const float*)d_in[15];
  const float* f2_w = (const float*)d_in[16]; const float* f2_b = (const float*)d_in[17];
  const float* sim_alpha = (const float*)d_in[18];
  const float* sim_beta  = (const float*)d_in[19];

  char* ws = (char*)d_ws;
  #define SLOT(i) (ws + (size_t)(i) * 16777216)
  f16* cth = (f16*)SLOT(0);
  f16* ctl = (f16*)SLOT(1);
  f16* sth = (f16*)SLOT(2);
  f16* stl = (f16*)SLOT(3);
  f16* wbase = (f16*)SLOT(4);
  f16* qw   = wbase;
  f16* kw   = wbase + 1 * 1048576;
  f16* q2wh = wbase + 2 * 1048576;
  f16* q2wl = wbase + 3 * 1048576;
  f16* k2wh = wbase + 4 * 1048576;
  f16* k2wl = wbase + 5 * 1048576;
  f16* vw   = wbase + 6 * 1048576;
  f16* v2w  = vw + 262144;
  f16* f1w  = vw + 524288;
  f16* f2w  = vw + 786432;
  f16*   q2h   = (f16*)SLOT(5);
  f16*   q2l   = (f16*)SLOT(6);
  f16*   k2h   = (f16*)SLOT(7);
  f16*   k2l   = (f16*)SLOT(0);      // after content convs
  f16*   qbuf  = (f16*)SLOT(1);      // after q2 conv
  float* pa1p  = (float*)SLOT(3);    // after k2 conv (4 MB)
  f16*   kbuf  = (f16*)SLOT(6);      // after pa1
  f16*   vbuf  = (f16*)SLOT(3);      // after pa1r
  f16*   v2buf = (f16*)SLOT(0);      // after pa1
  f16*   da_t  = (f16*)SLOT(3);      // after da1
  f16*   pa_t  = (f16*)SLOT(6);      // after da1
  float* stats = (float*)(ws + 134217728);
  float* biasp = (float*)(ws + 134217728 + 32768);
  float* kagg  = (float*)(ws + 134217728 + 32768);
  float* vagg  = (float*)(ws + 134217728 + 557056);
  int*   idxb  = (int*)(ws + 134217728 + 1081344);

  dim3 gconv(32, 4, 4);

  k_mvn_stats<<<4096, 256, 0, stream>>>(content, style, stats);

  k_prep_w_all<<<320, 256, 0, stream>>>(
      q_w, q_b, k_w, k_b, q2_w, q2_b, k2_w, k2_b,
      v_w, v_b, v2_w, v2_b, f1_w, f2_w, stats,
      qw, kw, q2wh, q2wl, k2wh, k2wl, vw, v2w, f1w, f2w, biasp);

  k_prep_x<<<dim3(32,4,2), 256, 0, stream>>>(content, style, cth, ctl, sth, stl);

  // content convs
  k_convT3<<<gconv, 256, 0, stream>>>(cth, ctl, q2wh, q2wl, biasp + 4 * 2048, q2h, q2l);
  k_convT <<<gconv, 256, 0, stream>>>(cth, qw, biasp + 0 * 2048, 1, qbuf);
  // style split conv, then PA1 (frees q2l/k2l)
  k_convT3<<<gconv, 256, 0, stream>>>(sth, stl, k2wh, k2wl, biasp + 5 * 2048, k2h, k2l);
  k_pa1<<<256, 256, 0, stream>>>(q2h, q2l, k2h, k2l, pa1p);
  k_pa1r<<<32, 64, 0, stream>>>(pa1p, idxb);
  // fused k/v/v2 style convs
  k_conv3out<<<dim3(32,12,4), 256, 0, stream>>>(sth, kw, vw, v2w, biasp,
                                                kbuf, vbuf, v2buf);

  k_da1<<<2048, 256, 0, stream>>>(kbuf, vbuf, sim_alpha, sim_beta, kagg, vagg);
  k_da2<<<512, 256, 0, stream>>>(qbuf, kagg, vagg, da_t);
  k_pa2<<<2048, 256, 0, stream>>>(q2h, k2h, v2buf, idxb, pa_t);

  k_finalT<<<gconv, 256, 0, stream>>>(da_t, pa_t, f1w, f2w, f1_b, f2_b,
                                      content, (float*)d_out);
}